// Round 13
// baseline (813.363 us; speedup 1.0000x reference)
//
#include <hip/hip_runtime.h>
#include <hip/hip_bf16.h>

#define NDENSE 13
#define NSPARSE 26
#define NFEAT 39
#define EDIM 64
#define NLAYER 4
#define FFDIM 256
#define VDN 50
#define VSN 50000
#define NSAMP 8192
#define LN_EPS 1e-5f

// Q pre-scale: HD^-0.5 * log2(e), folded into wqT/bq' at pack time
#define QSCL 0.5100697f
// gelu: x * sigmoid2(C1*x + C2*x^3), constants pre-multiplied by log2(e)
#define GC1 2.3022082f
#define GC2 0.10294324f

#define XST 72     // xb row stride (bf16), 144 B
#define QST 72     // Qb/Kb row stride
#define VST2 56    // Vt row stride (112 B, 16B-mult)
#define FST2 136   // ff row stride (272 B, 16B-mult)
#define SSTB 72    // S-staging row stride in BYTES (18 words -> 16-bank orbit)

// LDS layout (bytes) — 1 sample / block
#define OFF_XB 0             // xb [40][72]  = 5760
#define OFF_QB 5760          // Qb [48][72]  = 6912  (S-staging in A2; O after attn; ff in A4)
#define OFF_KB 12672         // Kb [48][72]  = 6912  (staging tail / ff tail)
#define OFF_VT 19584         // Vt [64][56]  = 7168  (LN scratch in A1/A4)
#define SMEM_TOTAL 26752
#define OFF_FF OFF_QB        // ff [48][136] = 13056 <= Qb+Kb = 13824
#define OFF_LNS OFF_VT       // LN rows [48][72] = 6912 <= 7168

// ---- packed (transposed, bf16, gamma/QSCL-folded) weights in d_ws after flatX ----
#define FLATX_ELEMS (8192L * NFEAT * EDIM)
#define PK_WKT 4096
#define PK_WVT 8192
#define PK_WOT 12288
#define PK_W1T 16384
#define PK_W2T 32768
#define PK_LAYER 49152
#define PK_OW1T 196608
#define PK_TOTAL 835584
#define FB_PER_LAYER 448     // folded biases: bq'(64) bk'(64) bv'(64) b1'(256), f32

typedef __bf16 bf16x8 __attribute__((ext_vector_type(8)));
typedef __bf16 bf16x4 __attribute__((ext_vector_type(4)));
typedef float f32x4 __attribute__((ext_vector_type(4)));

__device__ __forceinline__ f32x4 mfma16(bf16x8 a, bf16x8 b, f32x4 c) {
    return __builtin_amdgcn_mfma_f32_16x16x32_bf16(a, b, c, 0, 0, 0);
}

__device__ __forceinline__ float exp2_fast(float x) {
#if __has_builtin(__builtin_amdgcn_exp2f)
    return __builtin_amdgcn_exp2f(x);
#else
    return exp2f(x);
#endif
}
__device__ __forceinline__ float sigmoid2(float x) {
    return __builtin_amdgcn_rcpf(1.0f + exp2_fast(-x));
}
__device__ __forceinline__ float gelu_f(float x) {
    return x * sigmoid2(GC1 * x + GC2 * x * x * x);
}

__device__ __forceinline__ bf16x8 ldfrag(const __bf16* WT, int ld, int col, int k0) {
    return *(const bf16x8*)&WT[col * ld + k0];
}
__device__ __forceinline__ bf16x4 pk4(f32x4 v) {
    bf16x4 r; r[0]=(__bf16)v[0]; r[1]=(__bf16)v[1]; r[2]=(__bf16)v[2]; r[3]=(__bf16)v[3]; return r;
}
__device__ __forceinline__ void rmw4(__bf16* p, f32x4 a) {
    bf16x4 o = *(bf16x4*)p;
    f32x4 n = { (float)o[0]+a[0], (float)o[1]+a[1], (float)o[2]+a[2], (float)o[3]+a[3] };
    *(bf16x4*)p = pk4(n);
}

// Cooperative row-normalize of xb rows 0..47 (clamped) into LNS [48][72].
// 12 units over 4 waves; unit u handles rows 4u+g; 16 lanes (r16) x 4 cols each.
__device__ __forceinline__ void coop_ln(const __bf16* xb, __bf16* LNS,
                                        int w, int g, int r16) {
    for (int u = w; u < 12; u += 4) {
        int ql = 4 * u + g;
        int qlc = ql > 39 ? 39 : ql;
        bf16x4 v = *(const bf16x4*)&xb[qlc * XST + 4 * r16];
        float x0 = (float)v[0], x1 = (float)v[1], x2 = (float)v[2], x3 = (float)v[3];
        float s = x0 + x1 + x2 + x3;
        float ss = x0*x0 + x1*x1 + x2*x2 + x3*x3;
        s += __shfl_xor(s, 1);  ss += __shfl_xor(ss, 1);
        s += __shfl_xor(s, 2);  ss += __shfl_xor(ss, 2);
        s += __shfl_xor(s, 4);  ss += __shfl_xor(ss, 4);
        s += __shfl_xor(s, 8);  ss += __shfl_xor(ss, 8);
        float mn = s * (1.0f / 64.0f);
        float rs = rsqrtf(ss * (1.0f / 64.0f) - mn * mn + LN_EPS);
        f32x4 nv = { (x0 - mn) * rs, (x1 - mn) * rs,
                     (x2 - mn) * rs, (x3 - mn) * rs };
        *(bf16x4*)&LNS[ql * 72 + 4 * r16] = pk4(nv);
    }
}

// ---------------- weight pack: transpose + bf16, LN gamma (and QSCL) folded ----------------
__global__ __launch_bounds__(256)
void pack_weights(const float* __restrict__ wq, const float* __restrict__ wk,
                  const float* __restrict__ wv, const float* __restrict__ wo,
                  const float* __restrict__ w1, const float* __restrict__ w2,
                  const float* __restrict__ ow1, const float* __restrict__ ln1g,
                  const float* __restrict__ ln2g, __bf16* __restrict__ pk)
{
    int idx = blockIdx.x * 256 + threadIdx.x;
    if (idx >= PK_TOTAL) return;
    float v;
    if (idx < PK_OW1T) {
        int l = idx / PK_LAYER, r = idx - l * PK_LAYER;
        const float* src; const float* gam = nullptr; int sh, N, off;
        float extra = 1.0f;
        if (r < PK_WKT)      { src = wq + l * 4096;  sh = 6; N = 64;  off = r;           gam = ln1g + l*64; extra = QSCL; }
        else if (r < PK_WVT) { src = wk + l * 4096;  sh = 6; N = 64;  off = r - PK_WKT;  gam = ln1g + l*64; }
        else if (r < PK_WOT) { src = wv + l * 4096;  sh = 6; N = 64;  off = r - PK_WVT;  gam = ln1g + l*64; }
        else if (r < PK_W1T) { src = wo + l * 4096;  sh = 6; N = 64;  off = r - PK_WOT; }
        else if (r < PK_W2T) { src = w1 + l * 16384; sh = 6; N = 256; off = r - PK_W1T;  gam = ln2g + l*64; }
        else                 { src = w2 + l * 16384; sh = 8; N = 64;  off = r - PK_W2T; }
        int col = off >> sh, k = off & ((1 << sh) - 1);
        v = src[k * N + col] * extra;
        if (gam) v *= gam[k];
    } else {
        int off = idx - PK_OW1T;
        int col = off / 2496, k = off - col * 2496;
        v = ow1[k * 256 + col];
    }
    pk[idx] = (__bf16)v;
}

// ---------------- bias fold: b' = (b + beta @ W) [* QSCL for q] (f32) ----------------
__global__ __launch_bounds__(256)
void fold_bias(const float* __restrict__ wq, const float* __restrict__ wk,
               const float* __restrict__ wv, const float* __restrict__ w1,
               const float* __restrict__ bq, const float* __restrict__ bk,
               const float* __restrict__ bv, const float* __restrict__ b1,
               const float* __restrict__ ln1b, const float* __restrict__ ln2b,
               float* __restrict__ pkb)
{
    int idx = blockIdx.x * 256 + threadIdx.x;
    if (idx >= NLAYER * FB_PER_LAYER) return;
    int l = idx / FB_PER_LAYER, r = idx - l * FB_PER_LAYER;
    const float *W, *b, *beta; int col, N; float extra = 1.0f;
    if (r < 64)       { W = wq + l*4096;  b = bq + l*64;  beta = ln1b + l*64; col = r;       N = 64;  extra = QSCL; }
    else if (r < 128) { W = wk + l*4096;  b = bk + l*64;  beta = ln1b + l*64; col = r - 64;  N = 64;  }
    else if (r < 192) { W = wv + l*4096;  b = bv + l*64;  beta = ln1b + l*64; col = r - 128; N = 64;  }
    else              { W = w1 + l*16384; b = b1 + l*256; beta = ln2b + l*64; col = r - 192; N = 256; }
    float acc = b[col];
    for (int k = 0; k < 64; ++k) acc += beta[k] * W[k * N + col];
    pkb[idx] = acc * extra;
}

// ---------------- fused 4-layer transformer, 1 sample / block, 4 waves ----------------
__global__ __launch_bounds__(256, 6)
void hstu_fused(const int* __restrict__ dfeat, const int* __restrict__ sfeat,
                const float* __restrict__ demb, const float* __restrict__ semb,
                const float* __restrict__ bo, const float* __restrict__ b2,
                const __bf16* __restrict__ pk, const float* __restrict__ pkb,
                __bf16* __restrict__ flatX)
{
    __shared__ __align__(16) char smem[SMEM_TOTAL];
    __bf16* xb  = (__bf16*)(smem + OFF_XB);
    __bf16* Qb  = (__bf16*)(smem + OFF_QB);
    __bf16* Kb  = (__bf16*)(smem + OFF_KB);
    __bf16* Vt  = (__bf16*)(smem + OFF_VT);
    __bf16* ff  = (__bf16*)(smem + OFF_FF);
    __bf16* LNS = (__bf16*)(smem + OFF_LNS);

    const int tid = threadIdx.x;
    const int lane = tid & 63, w = tid >> 6;       // 4 waves
    const int g = lane >> 4, r16 = lane & 15;
    const int oc = w;                              // 16-col output strip
    const int s0 = blockIdx.x;                     // one sample

    // ---------------- embedding gather (row 39 = zero pad) ----------------
    for (int r = w; r < 40; r += 4) {
        float val = 0.0f;
        if (r < NFEAT) {
            if (r < NDENSE) {
                int idx = dfeat[s0 * NDENSE + r];
                val = demb[(r * VDN + idx) * EDIM + lane];
            } else {
                int idx = sfeat[s0 * NSPARSE + (r - NDENSE)];
                val = semb[((long)(r - NDENSE) * VSN + idx) * EDIM + lane];
            }
        }
        xb[r * XST + lane] = (__bf16)val;
    }
    __syncthreads();

    for (int lay = 0; lay < NLAYER; ++lay) {
        const __bf16* wqT = pk + lay * PK_LAYER;
        const __bf16* wkT = wqT + PK_WKT;
        const __bf16* wvT = wqT + PK_WVT;
        const __bf16* woT = wqT + PK_WOT;
        const __bf16* w1T = wqT + PK_W1T;
        const __bf16* w2T = wqT + PK_W2T;
        const float* fb   = pkb + lay * FB_PER_LAYER;   // bq' bk' bv' b1'
        const float* bo_l = bo + lay * EDIM;
        const float* b2_l = b2 + lay * EDIM;

        // ---- A1: cooperative LN1 -> LNS (=Vt, free now), then QKV projection ----
        coop_ln(xb, LNS, w, g, r16);
        __syncthreads();   // LNS ready

        bf16x8 lnB[3][2];
        #pragma unroll
        for (int tt = 0; tt < 3; ++tt) {
            lnB[tt][0] = *(const bf16x8*)&LNS[(16 * tt + r16) * 72 + 8 * g];
            lnB[tt][1] = *(const bf16x8*)&LNS[(16 * tt + r16) * 72 + 32 + 8 * g];
        }
        __syncthreads();   // all frags loaded; Vt may be overwritten now

        {
            const __bf16* Wm[3] = { wqT, wkT, wvT };
            #pragma unroll
            for (int m = 0; m < 3; ++m) {
                bf16x8 A0 = ldfrag(Wm[m], EDIM, 16 * oc + r16, 8 * g);
                bf16x8 A1 = ldfrag(Wm[m], EDIM, 16 * oc + r16, 32 + 8 * g);
                f32x4 bi4 = *(const f32x4*)&fb[m * 64 + 16 * oc + 4 * g];
                #pragma unroll
                for (int tt = 0; tt < 3; ++tt) {
                    f32x4 acc = bi4;
                    acc = mfma16(A0, lnB[tt][0], acc);
                    acc = mfma16(A1, lnB[tt][1], acc);
                    int q48 = 16 * tt + r16;
                    if (m == 0) {
                        *(bf16x4*)&Qb[q48 * QST + 16 * oc + 4 * g] = pk4(acc);
                    } else if (m == 1) {
                        *(bf16x4*)&Kb[q48 * QST + 16 * oc + 4 * g] = pk4(acc);
                    } else {
                        bool vz = q48 >= 39;   // zero pad token cols
                        #pragma unroll
                        for (int r = 0; r < 4; ++r)
                            Vt[(16 * oc + 4 * g + r) * VST2 + q48] =
                                vz ? (__bf16)0.0f : (__bf16)acc[r];
                    }
                }
            }
        }
        __syncthreads();   // B1: Q/K/Vt ready

        // ---- A2: attention; wave -> heads 2oc, 2oc+1; S via per-wave LDS staging ----
        {
            // preload all Q/K fragments (g==0 lanes hold data), then Qb/Kb become staging
            bf16x8 qf[2][3], kf[2][3];
            #pragma unroll
            for (int hh = 0; hh < 2; ++hh) {
                #pragma unroll
                for (int t = 0; t < 3; ++t) {
                    bf16x8 z = {};
                    qf[hh][t] = z; kf[hh][t] = z;
                    if (g == 0) {
                        qf[hh][t] = *(const bf16x8*)&Qb[(16*t + r16) * QST + 8*(2*oc + hh)];
                        kf[hh][t] = *(const bf16x8*)&Kb[(16*t + r16) * QST + 8*(2*oc + hh)];
                    }
                }
            }
            __syncthreads();   // Qb/Kb free -> per-wave S staging

            // staging: per wave [48 q] rows of 72 B (32 kk bf16 + 8 B pad).
            // 72 B = 18 words -> 16 consecutive q hit 16 distinct banks (conflict-free).
            char* st = (char*)Qb + w * (48 * SSTB);

            const int sAh[3] = {0,0,1}, sAt[3] = {0,2,1};   // ts=0 tile (hh,kt) per ks
            const int sBh[3] = {0,1,1}, sBt[3] = {1,0,2};   // ts=1 tile
            f32x4 oacc[3];
            {
                f32x4 z = {0.f, 0.f, 0.f, 0.f};
                oacc[0] = z; oacc[1] = z; oacc[2] = z;
            }
            #pragma unroll
            for (int ks = 0; ks < 3; ++ks) {
                // stage the two S^T tiles of this ks: D[kk_loc=4g+r][q=r16] per qt
                #pragma unroll
                for (int ts = 0; ts < 2; ++ts) {
                    int hh = ts ? sBh[ks] : sAh[ks];
                    int kt = ts ? sBt[ks] : sAt[ks];
                    #pragma unroll
                    for (int qt = 0; qt < 3; ++qt) {
                        f32x4 acc = {0.f, 0.f, 0.f, 0.f};
                        acc = mfma16(kf[hh][kt], qf[hh][qt], acc);
                        f32x4 sg = { sigmoid2(acc[0]), sigmoid2(acc[1]),
                                     sigmoid2(acc[2]), sigmoid2(acc[3]) };
                        int q = 16 * qt + r16;
                        int off = q * SSTB + (2 * ts + (g >> 1)) * 16 + (g & 1) * 8;
                        *(bf16x4*)(st + off) = pk4(sg);
                    }
                }
                // PV: A = Vt (head-masked), B = staged S^T (slot_loc = 8g+j)
                int slot0 = 32 * ks + 8 * g;
                int side = slot0 >= 48 ? 1 : 0;
                int kk0 = slot0 - 48 * side;
                bf16x8 av = {};
                if (side == (r16 >> 3))
                    av = *(const bf16x8*)&Vt[(16 * oc + r16) * VST2 + kk0];
                #pragma unroll
                for (int qt = 0; qt < 3; ++qt) {
                    int q = 16 * qt + r16;
                    bf16x8 bfrag = *(const bf16x8*)(st + q * SSTB + g * 16);
                    oacc[qt] = mfma16(av, bfrag, oacc[qt]);
                }
            }
            __syncthreads();   // all PV staging reads done -> Qb free for O

            // O overwrites Qb (this wave's column strip)
            #pragma unroll
            for (int qt = 0; qt < 3; ++qt) {
                int q48 = 16 * qt + r16;
                *(bf16x4*)&Qb[q48 * QST + 16 * oc + 4 * g] = pk4(oacc[qt]);
            }
        }
        __syncthreads();   // B2: O complete

        // ---- A3: O-proj + residual; wave -> outcol tile oc ----
        {
            bf16x8 A0 = ldfrag(woT, EDIM, 16 * oc + r16, 8 * g);
            bf16x8 A1 = ldfrag(woT, EDIM, 16 * oc + r16, 32 + 8 * g);
            f32x4 bo4 = *(const f32x4*)&bo_l[16 * oc + 4 * g];
            #pragma unroll
            for (int tt = 0; tt < 3; ++tt) {
                bf16x8 B0 = *(const bf16x8*)&Qb[(16 * tt + r16) * QST + 8 * g];
                bf16x8 B1 = *(const bf16x8*)&Qb[(16 * tt + r16) * QST + 32 + 8 * g];
                f32x4 acc = bo4;
                acc = mfma16(A0, B0, acc);
                acc = mfma16(A1, B1, acc);
                int ql = 16 * tt + r16;
                if (ql <= 39)
                    rmw4(&xb[ql * XST + 16 * oc + 4 * g], acc);
            }
        }
        __syncthreads();   // B3: xb updated; Qb/Kb (ff) and Vt (LNS) free

        // ---- A4: MLP; cooperative LN2 -> LNS, FF in two 128-col passes ----
        coop_ln(xb, LNS, w, g, r16);
        __syncthreads();   // LNS ready

        {
            bf16x8 upB[3][2];
            #pragma unroll
            for (int tt = 0; tt < 3; ++tt) {
                upB[tt][0] = *(const bf16x8*)&LNS[(16 * tt + r16) * 72 + 8 * g];
                upB[tt][1] = *(const bf16x8*)&LNS[(16 * tt + r16) * 72 + 32 + 8 * g];
            }
            f32x4 acc2[3];
            acc2[0] = *(const f32x4*)&b2_l[16 * oc + 4 * g];
            acc2[1] = acc2[0]; acc2[2] = acc2[0];

            #pragma unroll
            for (int p2 = 0; p2 < 2; ++p2) {
                // up: wave -> 2 local ffcol tiles of this 128-col pass
                #pragma unroll
                for (int fi = 0; fi < 2; ++fi) {
                    int ftl = 2 * w + fi;           // local tile 0..7
                    int ftg = 8 * p2 + ftl;         // global tile 0..15
                    bf16x8 A0 = ldfrag(w1T, EDIM, 16 * ftg + r16, 8 * g);
                    bf16x8 A1 = ldfrag(w1T, EDIM, 16 * ftg + r16, 32 + 8 * g);
                    f32x4 b14 = *(const f32x4*)&fb[192 + 16 * ftg + 4 * g];
                    #pragma unroll
                    for (int tt = 0; tt < 3; ++tt) {
                        f32x4 acc = b14;
                        acc = mfma16(A0, upB[tt][0], acc);
                        acc = mfma16(A1, upB[tt][1], acc);
                        f32x4 gl = { gelu_f(acc[0]), gelu_f(acc[1]),
                                     gelu_f(acc[2]), gelu_f(acc[3]) };
                        *(bf16x4*)&ff[(16 * tt + r16) * FST2 + 16 * ftl + 4 * g] = pk4(gl);
                    }
                }
                __syncthreads();   // ff pass ready

                // down: wave -> outcol tile oc, accumulate across passes
                #pragma unroll
                for (int tt = 0; tt < 3; ++tt) {
                    #pragma unroll
                    for (int kf2 = 0; kf2 < 4; ++kf2) {
                        bf16x8 Af = ldfrag(w2T, FFDIM, 16 * oc + r16,
                                           128 * p2 + 32 * kf2 + 8 * g);
                        bf16x8 Bf = *(const bf16x8*)&ff[(16 * tt + r16) * FST2
                                                        + 32 * kf2 + 8 * g];
                        acc2[tt] = mfma16(Af, Bf, acc2[tt]);
                    }
                }
                __syncthreads();   // ff consumed; next pass may overwrite
            }
            // residual add
            #pragma unroll
            for (int tt = 0; tt < 3; ++tt) {
                int ql = 16 * tt + r16;
                if (ql <= 39)
                    rmw4(&xb[ql * XST + 16 * oc + 4 * g], acc2[tt]);
            }
        }
        __syncthreads();   // layer end: xb complete
    }

    // ---------------- write flat activations ----------------
    for (int r = w; r < NFEAT; r += 4)
        flatX[((long)s0 * NFEAT + r) * EDIM + lane] = xb[r * XST + lane];
}

// ---------------- head MLP ----------------
#define FFSTH 264
__global__ __launch_bounds__(512)
void final_mlp(const __bf16* __restrict__ flatX, const __bf16* __restrict__ ow1T,
               const float* __restrict__ ob1, const float* __restrict__ ow2,
               const float* __restrict__ ob2, float* __restrict__ out)
{
    __shared__ __bf16 hbuf[32 * FFSTH];
    const int tid = threadIdx.x, lane = tid & 63, wave = tid >> 6;
    const int g = lane >> 4, r16 = lane & 15;
    const int m = wave & 1;
    const long base = (long)blockIdx.x * 32;
    const long arow = (base + m * 16 + r16) * (long)(NFEAT * EDIM);

    f32x4 acc[4];
    #pragma unroll
    for (int i = 0; i < 4; ++i) {
        int n = (wave >> 1) + i * 4;
        float bz = ob1[n * 16 + r16];
        f32x4 t = {bz, bz, bz, bz};
        acc[i] = t;
    }
    for (int kf = 0; kf < 78; ++kf) {
        bf16x8 af = *(const bf16x8*)&flatX[arow + kf * 32 + g * 8];
        #pragma unroll
        for (int i = 0; i < 4; ++i) {
            int n = (wave >> 1) + i * 4;
            bf16x8 bfr = ldfrag(ow1T, NFEAT * EDIM, n * 16 + r16, kf * 32 + g * 8);
            acc[i] = mfma16(af, bfr, acc[i]);
        }
    }
    #pragma unroll
    for (int i = 0; i < 4; ++i) {
        int n = (wave >> 1) + i * 4;
        #pragma unroll
        for (int r = 0; r < 4; ++r) {
            float h = acc[i][r];
            hbuf[(m * 16 + g * 4 + r) * FFSTH + n * 16 + r16] = (__bf16)(h > 0.f ? h : 0.f);
        }
    }
    __syncthreads();
    float w2v0 = ow2[lane], w2v1 = ow2[64 + lane], w2v2 = ow2[128 + lane], w2v3 = ow2[192 + lane];
    float bias2 = ob2[0];
    #pragma unroll
    for (int i = 0; i < 4; ++i) {
        int sm = wave * 4 + i;
        float part = (float)hbuf[sm * FFSTH + lane]       * w2v0
                   + (float)hbuf[sm * FFSTH + 64 + lane]  * w2v1
                   + (float)hbuf[sm * FFSTH + 128 + lane] * w2v2
                   + (float)hbuf[sm * FFSTH + 192 + lane] * w2v3;
        #pragma unroll
        for (int off = 32; off >= 1; off >>= 1) part += __shfl_xor(part, off);
        if (lane == 0) {
            float z = part + bias2;
            out[base + sm] = __builtin_amdgcn_rcpf(1.0f + __expf(-z));
        }
    }
}

extern "C" void kernel_launch(void* const* d_in, const int* in_sizes, int n_in,
                              void* d_out, int out_size, void* d_ws, size_t ws_size,
                              hipStream_t stream)
{
    const int*   dfeat = (const int*)d_in[0];
    const int*   sfeat = (const int*)d_in[1];
    const float* demb  = (const float*)d_in[2];
    const float* semb  = (const float*)d_in[3];
    const float* wq    = (const float*)d_in[4];
    const float* bq    = (const float*)d_in[5];
    const float* wk    = (const float*)d_in[6];
    const float* bk    = (const float*)d_in[7];
    const float* wv    = (const float*)d_in[8];
    const float* bv    = (const float*)d_in[9];
    const float* wo    = (const float*)d_in[10];
    const float* bo    = (const float*)d_in[11];
    const float* ln1g  = (const float*)d_in[12];
    const float* ln1b  = (const float*)d_in[13];
    const float* ln2g  = (const float*)d_in[14];
    const float* ln2b  = (const float*)d_in[15];
    const float* w1    = (const float*)d_in[16];
    const float* b1    = (const float*)d_in[17];
    const float* w2    = (const float*)d_in[18];
    const float* b2    = (const float*)d_in[19];
    const float* ow1   = (const float*)d_in[20];
    const float* ob1   = (const float*)d_in[21];
    const float* ow2   = (const float*)d_in[22];
    const float* ob2   = (const float*)d_in[23];

    __bf16* flatX = (__bf16*)d_ws;
    __bf16* pk    = ((__bf16*)d_ws) + FLATX_ELEMS;
    float*  pkb   = (float*)(pk + PK_TOTAL);      // folded biases, 1792 f32
    float* out = (float*)d_out;

    pack_weights<<<(PK_TOTAL + 255) / 256, 256, 0, stream>>>(wq, wk, wv, wo, w1, w2,
                                                             ow1, ln1g, ln2g, pk);
    fold_bias<<<(NLAYER * FB_PER_LAYER + 255) / 256, 256, 0, stream>>>(
        wq, wk, wv, w1, bq, bk, bv, b1, ln1b, ln2b, pkb);
    hstu_fused<<<NSAMP, 256, 0, stream>>>(dfeat, sfeat, demb, semb,
                                          bo, b2, pk, pkb, flatX);
    final_mlp<<<NSAMP / 32, 512, 0, stream>>>(flatX, pk + PK_OW1T, ob1, ow2, ob2, out);
}

// Round 14
// 727.610 us; speedup vs baseline: 1.1179x; 1.1179x over previous
//
#include <hip/hip_runtime.h>
#include <hip/hip_bf16.h>

#define NDENSE 13
#define NSPARSE 26
#define NFEAT 39
#define EDIM 64
#define NLAYER 4
#define FFDIM 256
#define VDN 50
#define VSN 50000
#define NSAMP 8192
#define LN_EPS 1e-5f

// Q pre-scale: HD^-0.5 * log2(e), folded into wqT/bq' at pack time
#define QSCL 0.5100697f
// gelu: x * sigmoid2(C1*x + C2*x^3), constants pre-multiplied by log2(e)
#define GC1 2.3022082f
#define GC2 0.10294324f

#define XST 72     // xb row stride (bf16), 144 B
#define QST 72     // Qb/Kb row stride
#define VST2 56    // Vt row stride (112 B, 16B-mult)
#define FST2 136   // ff row stride (272 B, 16B-mult)
#define SSTB 72    // S-staging row stride in BYTES (18 words -> 16-bank orbit)

// LDS layout (bytes) — 1 sample / block
#define OFF_XB 0             // xb [40][72]  = 5760
#define OFF_QB 5760          // Qb [48][72]  = 6912  (S-staging in A2; O after attn; ff in A4)
#define OFF_KB 12672         // Kb [48][72]  = 6912  (staging tail / ff tail)
#define OFF_VT 19584         // Vt [64][56]  = 7168  (LN scratch in A1/A4)
#define SMEM_TOTAL 26752
#define OFF_FF OFF_QB        // ff [48][136] = 13056 <= Qb+Kb = 13824
#define OFF_LNS OFF_VT       // LN rows [48][72] = 6912 <= 7168

// ---- packed (transposed, bf16, gamma/QSCL-folded) weights in d_ws after flatX ----
#define FLATX_ELEMS (8192L * NFEAT * EDIM)
#define PK_WKT 4096
#define PK_WVT 8192
#define PK_WOT 12288
#define PK_W1T 16384
#define PK_W2T 32768
#define PK_LAYER 49152
#define PK_OW1T 196608
#define PK_TOTAL 835584
#define FB_PER_LAYER 448     // folded biases: bq'(64) bk'(64) bv'(64) b1'(256), f32

typedef __bf16 bf16x8 __attribute__((ext_vector_type(8)));
typedef __bf16 bf16x4 __attribute__((ext_vector_type(4)));
typedef float f32x4 __attribute__((ext_vector_type(4)));

__device__ __forceinline__ f32x4 mfma16(bf16x8 a, bf16x8 b, f32x4 c) {
    return __builtin_amdgcn_mfma_f32_16x16x32_bf16(a, b, c, 0, 0, 0);
}

__device__ __forceinline__ float exp2_fast(float x) {
#if __has_builtin(__builtin_amdgcn_exp2f)
    return __builtin_amdgcn_exp2f(x);
#else
    return exp2f(x);
#endif
}
__device__ __forceinline__ float sigmoid2(float x) {
    return __builtin_amdgcn_rcpf(1.0f + exp2_fast(-x));
}
__device__ __forceinline__ float gelu_f(float x) {
    return x * sigmoid2(GC1 * x + GC2 * x * x * x);
}

__device__ __forceinline__ bf16x8 ldfrag(const __bf16* WT, int ld, int col, int k0) {
    return *(const bf16x8*)&WT[col * ld + k0];
}
__device__ __forceinline__ bf16x4 pk4(f32x4 v) {
    bf16x4 r; r[0]=(__bf16)v[0]; r[1]=(__bf16)v[1]; r[2]=(__bf16)v[2]; r[3]=(__bf16)v[3]; return r;
}
__device__ __forceinline__ void rmw4(__bf16* p, f32x4 a) {
    bf16x4 o = *(bf16x4*)p;
    f32x4 n = { (float)o[0]+a[0], (float)o[1]+a[1], (float)o[2]+a[2], (float)o[3]+a[3] };
    *(bf16x4*)p = pk4(n);
}

// Cooperative row-normalize of xb rows 0..47 (clamped) into LNS [48][72].
// 12 units over 4 waves; unit u handles rows 4u+g; 16 lanes (r16) x 4 cols each.
__device__ __forceinline__ void coop_ln(const __bf16* xb, __bf16* LNS,
                                        int w, int g, int r16) {
    for (int u = w; u < 12; u += 4) {
        int ql = 4 * u + g;
        int qlc = ql > 39 ? 39 : ql;
        bf16x4 v = *(const bf16x4*)&xb[qlc * XST + 4 * r16];
        float x0 = (float)v[0], x1 = (float)v[1], x2 = (float)v[2], x3 = (float)v[3];
        float s = x0 + x1 + x2 + x3;
        float ss = x0*x0 + x1*x1 + x2*x2 + x3*x3;
        s += __shfl_xor(s, 1);  ss += __shfl_xor(ss, 1);
        s += __shfl_xor(s, 2);  ss += __shfl_xor(ss, 2);
        s += __shfl_xor(s, 4);  ss += __shfl_xor(ss, 4);
        s += __shfl_xor(s, 8);  ss += __shfl_xor(ss, 8);
        float mn = s * (1.0f / 64.0f);
        float rs = rsqrtf(ss * (1.0f / 64.0f) - mn * mn + LN_EPS);
        f32x4 nv = { (x0 - mn) * rs, (x1 - mn) * rs,
                     (x2 - mn) * rs, (x3 - mn) * rs };
        *(bf16x4*)&LNS[ql * 72 + 4 * r16] = pk4(nv);
    }
}

// ---------------- weight pack: transpose + bf16, LN gamma (and QSCL) folded ----------------
__global__ __launch_bounds__(256)
void pack_weights(const float* __restrict__ wq, const float* __restrict__ wk,
                  const float* __restrict__ wv, const float* __restrict__ wo,
                  const float* __restrict__ w1, const float* __restrict__ w2,
                  const float* __restrict__ ow1, const float* __restrict__ ln1g,
                  const float* __restrict__ ln2g, __bf16* __restrict__ pk)
{
    int idx = blockIdx.x * 256 + threadIdx.x;
    if (idx >= PK_TOTAL) return;
    float v;
    if (idx < PK_OW1T) {
        int l = idx / PK_LAYER, r = idx - l * PK_LAYER;
        const float* src; const float* gam = nullptr; int sh, N, off;
        float extra = 1.0f;
        if (r < PK_WKT)      { src = wq + l * 4096;  sh = 6; N = 64;  off = r;           gam = ln1g + l*64; extra = QSCL; }
        else if (r < PK_WVT) { src = wk + l * 4096;  sh = 6; N = 64;  off = r - PK_WKT;  gam = ln1g + l*64; }
        else if (r < PK_WOT) { src = wv + l * 4096;  sh = 6; N = 64;  off = r - PK_WVT;  gam = ln1g + l*64; }
        else if (r < PK_W1T) { src = wo + l * 4096;  sh = 6; N = 64;  off = r - PK_WOT; }
        else if (r < PK_W2T) { src = w1 + l * 16384; sh = 6; N = 256; off = r - PK_W1T;  gam = ln2g + l*64; }
        else                 { src = w2 + l * 16384; sh = 8; N = 64;  off = r - PK_W2T; }
        int col = off >> sh, k = off & ((1 << sh) - 1);
        v = src[k * N + col] * extra;
        if (gam) v *= gam[k];
    } else {
        int off = idx - PK_OW1T;
        int col = off / 2496, k = off - col * 2496;
        v = ow1[k * 256 + col];
    }
    pk[idx] = (__bf16)v;
}

// ---------------- bias fold: b' = (b + beta @ W) [* QSCL for q] (f32) ----------------
__global__ __launch_bounds__(256)
void fold_bias(const float* __restrict__ wq, const float* __restrict__ wk,
               const float* __restrict__ wv, const float* __restrict__ w1,
               const float* __restrict__ bq, const float* __restrict__ bk,
               const float* __restrict__ bv, const float* __restrict__ b1,
               const float* __restrict__ ln1b, const float* __restrict__ ln2b,
               float* __restrict__ pkb)
{
    int idx = blockIdx.x * 256 + threadIdx.x;
    if (idx >= NLAYER * FB_PER_LAYER) return;
    int l = idx / FB_PER_LAYER, r = idx - l * FB_PER_LAYER;
    const float *W, *b, *beta; int col, N; float extra = 1.0f;
    if (r < 64)       { W = wq + l*4096;  b = bq + l*64;  beta = ln1b + l*64; col = r;       N = 64;  extra = QSCL; }
    else if (r < 128) { W = wk + l*4096;  b = bk + l*64;  beta = ln1b + l*64; col = r - 64;  N = 64;  }
    else if (r < 192) { W = wv + l*4096;  b = bv + l*64;  beta = ln1b + l*64; col = r - 128; N = 64;  }
    else              { W = w1 + l*16384; b = b1 + l*256; beta = ln2b + l*64; col = r - 192; N = 256; }
    float acc = b[col];
    for (int k = 0; k < 64; ++k) acc += beta[k] * W[k * N + col];
    pkb[idx] = acc * extra;
}

// ---------------- fused 4-layer transformer, 1 sample / block, 4 waves ----------------
__global__ __launch_bounds__(256, 4)
void hstu_fused(const int* __restrict__ dfeat, const int* __restrict__ sfeat,
                const float* __restrict__ demb, const float* __restrict__ semb,
                const float* __restrict__ bo, const float* __restrict__ b2,
                const __bf16* __restrict__ pk, const float* __restrict__ pkb,
                __bf16* __restrict__ flatX)
{
    __shared__ __align__(16) char smem[SMEM_TOTAL];
    __bf16* xb  = (__bf16*)(smem + OFF_XB);
    __bf16* Qb  = (__bf16*)(smem + OFF_QB);
    __bf16* Kb  = (__bf16*)(smem + OFF_KB);
    __bf16* Vt  = (__bf16*)(smem + OFF_VT);
    __bf16* ff  = (__bf16*)(smem + OFF_FF);
    __bf16* LNS = (__bf16*)(smem + OFF_LNS);

    const int tid = threadIdx.x;
    const int lane = tid & 63, w = tid >> 6;       // 4 waves
    const int g = lane >> 4, r16 = lane & 15;
    const int oc = w;                              // 16-col output strip
    const int s0 = blockIdx.x;                     // one sample

    // ---------------- embedding gather (row 39 = zero pad) ----------------
    for (int r = w; r < 40; r += 4) {
        float val = 0.0f;
        if (r < NFEAT) {
            if (r < NDENSE) {
                int idx = dfeat[s0 * NDENSE + r];
                val = demb[(r * VDN + idx) * EDIM + lane];
            } else {
                int idx = sfeat[s0 * NSPARSE + (r - NDENSE)];
                val = semb[((long)(r - NDENSE) * VSN + idx) * EDIM + lane];
            }
        }
        xb[r * XST + lane] = (__bf16)val;
    }
    __syncthreads();

    for (int lay = 0; lay < NLAYER; ++lay) {
        const __bf16* wqT = pk + lay * PK_LAYER;
        const __bf16* wkT = wqT + PK_WKT;
        const __bf16* wvT = wqT + PK_WVT;
        const __bf16* woT = wqT + PK_WOT;
        const __bf16* w1T = wqT + PK_W1T;
        const __bf16* w2T = wqT + PK_W2T;
        const float* fb   = pkb + lay * FB_PER_LAYER;   // bq' bk' bv' b1'
        const float* bo_l = bo + lay * EDIM;
        const float* b2_l = b2 + lay * EDIM;

        // ---- A1: cooperative LN1 -> LNS (=Vt, free now), then QKV projection ----
        coop_ln(xb, LNS, w, g, r16);
        __syncthreads();   // LNS ready

        bf16x8 lnB[3][2];
        #pragma unroll
        for (int tt = 0; tt < 3; ++tt) {
            lnB[tt][0] = *(const bf16x8*)&LNS[(16 * tt + r16) * 72 + 8 * g];
            lnB[tt][1] = *(const bf16x8*)&LNS[(16 * tt + r16) * 72 + 32 + 8 * g];
        }
        __syncthreads();   // all frags loaded; Vt may be overwritten now

        {
            const __bf16* Wm[3] = { wqT, wkT, wvT };
            #pragma unroll
            for (int m = 0; m < 3; ++m) {
                bf16x8 A0 = ldfrag(Wm[m], EDIM, 16 * oc + r16, 8 * g);
                bf16x8 A1 = ldfrag(Wm[m], EDIM, 16 * oc + r16, 32 + 8 * g);
                f32x4 bi4 = *(const f32x4*)&fb[m * 64 + 16 * oc + 4 * g];
                #pragma unroll
                for (int tt = 0; tt < 3; ++tt) {
                    f32x4 acc = bi4;
                    acc = mfma16(A0, lnB[tt][0], acc);
                    acc = mfma16(A1, lnB[tt][1], acc);
                    int q48 = 16 * tt + r16;
                    if (m == 0) {
                        *(bf16x4*)&Qb[q48 * QST + 16 * oc + 4 * g] = pk4(acc);
                    } else if (m == 1) {
                        *(bf16x4*)&Kb[q48 * QST + 16 * oc + 4 * g] = pk4(acc);
                    } else {
                        bool vz = q48 >= 39;   // zero pad token cols
                        #pragma unroll
                        for (int r = 0; r < 4; ++r)
                            Vt[(16 * oc + 4 * g + r) * VST2 + q48] =
                                vz ? (__bf16)0.0f : (__bf16)acc[r];
                    }
                }
            }
        }
        __syncthreads();   // B1: Q/K/Vt ready

        // ---- A2: attention; wave -> heads 2oc, 2oc+1; S via per-wave LDS staging ----
        {
            // preload all Q/K fragments (g==0 lanes hold data), then Qb/Kb become staging
            bf16x8 qf[2][3], kf[2][3];
            #pragma unroll
            for (int hh = 0; hh < 2; ++hh) {
                #pragma unroll
                for (int t = 0; t < 3; ++t) {
                    bf16x8 z = {};
                    qf[hh][t] = z; kf[hh][t] = z;
                    if (g == 0) {
                        qf[hh][t] = *(const bf16x8*)&Qb[(16*t + r16) * QST + 8*(2*oc + hh)];
                        kf[hh][t] = *(const bf16x8*)&Kb[(16*t + r16) * QST + 8*(2*oc + hh)];
                    }
                }
            }
            __syncthreads();   // Qb/Kb free -> per-wave S staging

            // staging: per wave [48 q] rows of 72 B (32 kk bf16 + 8 B pad).
            // 72 B = 18 words -> 16 consecutive q hit 16 distinct banks (conflict-free).
            char* st = (char*)Qb + w * (48 * SSTB);

            const int sAh[3] = {0,0,1}, sAt[3] = {0,2,1};   // ts=0 tile (hh,kt) per ks
            const int sBh[3] = {0,1,1}, sBt[3] = {1,0,2};   // ts=1 tile
            f32x4 oacc[3];
            {
                f32x4 z = {0.f, 0.f, 0.f, 0.f};
                oacc[0] = z; oacc[1] = z; oacc[2] = z;
            }
            #pragma unroll
            for (int ks = 0; ks < 3; ++ks) {
                // stage the two S^T tiles of this ks: D[kk_loc=4g+r][q=r16] per qt
                #pragma unroll
                for (int ts = 0; ts < 2; ++ts) {
                    int hh = ts ? sBh[ks] : sAh[ks];
                    int kt = ts ? sBt[ks] : sAt[ks];
                    #pragma unroll
                    for (int qt = 0; qt < 3; ++qt) {
                        f32x4 acc = {0.f, 0.f, 0.f, 0.f};
                        acc = mfma16(kf[hh][kt], qf[hh][qt], acc);
                        f32x4 sg = { sigmoid2(acc[0]), sigmoid2(acc[1]),
                                     sigmoid2(acc[2]), sigmoid2(acc[3]) };
                        int q = 16 * qt + r16;
                        int off = q * SSTB + (2 * ts + (g >> 1)) * 16 + (g & 1) * 8;
                        *(bf16x4*)(st + off) = pk4(sg);
                    }
                }
                // PV: A = Vt (head-masked), B = staged S^T (slot_loc = 8g+j)
                int slot0 = 32 * ks + 8 * g;
                int side = slot0 >= 48 ? 1 : 0;
                int kk0 = slot0 - 48 * side;
                bf16x8 av = {};
                if (side == (r16 >> 3))
                    av = *(const bf16x8*)&Vt[(16 * oc + r16) * VST2 + kk0];
                #pragma unroll
                for (int qt = 0; qt < 3; ++qt) {
                    int q = 16 * qt + r16;
                    bf16x8 bfrag = *(const bf16x8*)(st + q * SSTB + g * 16);
                    oacc[qt] = mfma16(av, bfrag, oacc[qt]);
                }
            }
            __syncthreads();   // all PV staging reads done -> Qb free for O

            // O overwrites Qb (this wave's column strip)
            #pragma unroll
            for (int qt = 0; qt < 3; ++qt) {
                int q48 = 16 * qt + r16;
                *(bf16x4*)&Qb[q48 * QST + 16 * oc + 4 * g] = pk4(oacc[qt]);
            }
        }
        __syncthreads();   // B2: O complete

        // ---- A3: O-proj + residual; wave -> outcol tile oc ----
        {
            bf16x8 A0 = ldfrag(woT, EDIM, 16 * oc + r16, 8 * g);
            bf16x8 A1 = ldfrag(woT, EDIM, 16 * oc + r16, 32 + 8 * g);
            f32x4 bo4 = *(const f32x4*)&bo_l[16 * oc + 4 * g];
            #pragma unroll
            for (int tt = 0; tt < 3; ++tt) {
                bf16x8 B0 = *(const bf16x8*)&Qb[(16 * tt + r16) * QST + 8 * g];
                bf16x8 B1 = *(const bf16x8*)&Qb[(16 * tt + r16) * QST + 32 + 8 * g];
                f32x4 acc = bo4;
                acc = mfma16(A0, B0, acc);
                acc = mfma16(A1, B1, acc);
                int ql = 16 * tt + r16;
                if (ql <= 39)
                    rmw4(&xb[ql * XST + 16 * oc + 4 * g], acc);
            }
        }
        __syncthreads();   // B3: xb updated; Qb/Kb (ff) and Vt (LNS) free

        // ---- A4: MLP; cooperative LN2 -> LNS, FF in two 128-col passes ----
        coop_ln(xb, LNS, w, g, r16);
        __syncthreads();   // LNS ready

        {
            bf16x8 upB[3][2];
            #pragma unroll
            for (int tt = 0; tt < 3; ++tt) {
                upB[tt][0] = *(const bf16x8*)&LNS[(16 * tt + r16) * 72 + 8 * g];
                upB[tt][1] = *(const bf16x8*)&LNS[(16 * tt + r16) * 72 + 32 + 8 * g];
            }
            f32x4 acc2[3];
            acc2[0] = *(const f32x4*)&b2_l[16 * oc + 4 * g];
            acc2[1] = acc2[0]; acc2[2] = acc2[0];

            #pragma unroll
            for (int p2 = 0; p2 < 2; ++p2) {
                // up: wave -> 2 local ffcol tiles of this 128-col pass
                #pragma unroll
                for (int fi = 0; fi < 2; ++fi) {
                    int ftl = 2 * w + fi;           // local tile 0..7
                    int ftg = 8 * p2 + ftl;         // global tile 0..15
                    bf16x8 A0 = ldfrag(w1T, EDIM, 16 * ftg + r16, 8 * g);
                    bf16x8 A1 = ldfrag(w1T, EDIM, 16 * ftg + r16, 32 + 8 * g);
                    f32x4 b14 = *(const f32x4*)&fb[192 + 16 * ftg + 4 * g];
                    #pragma unroll
                    for (int tt = 0; tt < 3; ++tt) {
                        f32x4 acc = b14;
                        acc = mfma16(A0, upB[tt][0], acc);
                        acc = mfma16(A1, upB[tt][1], acc);
                        f32x4 gl = { gelu_f(acc[0]), gelu_f(acc[1]),
                                     gelu_f(acc[2]), gelu_f(acc[3]) };
                        *(bf16x4*)&ff[(16 * tt + r16) * FST2 + 16 * ftl + 4 * g] = pk4(gl);
                    }
                }
                __syncthreads();   // ff pass ready

                // down: wave -> outcol tile oc, accumulate across passes
                #pragma unroll
                for (int tt = 0; tt < 3; ++tt) {
                    #pragma unroll
                    for (int kf2 = 0; kf2 < 4; ++kf2) {
                        bf16x8 Af = ldfrag(w2T, FFDIM, 16 * oc + r16,
                                           128 * p2 + 32 * kf2 + 8 * g);
                        bf16x8 Bf = *(const bf16x8*)&ff[(16 * tt + r16) * FST2
                                                        + 32 * kf2 + 8 * g];
                        acc2[tt] = mfma16(Af, Bf, acc2[tt]);
                    }
                }
                __syncthreads();   // ff consumed; next pass may overwrite
            }
            // residual add
            #pragma unroll
            for (int tt = 0; tt < 3; ++tt) {
                int ql = 16 * tt + r16;
                if (ql <= 39)
                    rmw4(&xb[ql * XST + 16 * oc + 4 * g], acc2[tt]);
            }
        }
        __syncthreads();   // layer end: xb complete
    }

    // ---------------- write flat activations ----------------
    for (int r = w; r < NFEAT; r += 4)
        flatX[((long)s0 * NFEAT + r) * EDIM + lane] = xb[r * XST + lane];
}

// ---------------- head MLP ----------------
#define FFSTH 264
__global__ __launch_bounds__(512)
void final_mlp(const __bf16* __restrict__ flatX, const __bf16* __restrict__ ow1T,
               const float* __restrict__ ob1, const float* __restrict__ ow2,
               const float* __restrict__ ob2, float* __restrict__ out)
{
    __shared__ __bf16 hbuf[32 * FFSTH];
    const int tid = threadIdx.x, lane = tid & 63, wave = tid >> 6;
    const int g = lane >> 4, r16 = lane & 15;
    const int m = wave & 1;
    const long base = (long)blockIdx.x * 32;
    const long arow = (base + m * 16 + r16) * (long)(NFEAT * EDIM);

    f32x4 acc[4];
    #pragma unroll
    for (int i = 0; i < 4; ++i) {
        int n = (wave >> 1) + i * 4;
        float bz = ob1[n * 16 + r16];
        f32x4 t = {bz, bz, bz, bz};
        acc[i] = t;
    }
    for (int kf = 0; kf < 78; ++kf) {
        bf16x8 af = *(const bf16x8*)&flatX[arow + kf * 32 + g * 8];
        #pragma unroll
        for (int i = 0; i < 4; ++i) {
            int n = (wave >> 1) + i * 4;
            bf16x8 bfr = ldfrag(ow1T, NFEAT * EDIM, n * 16 + r16, kf * 32 + g * 8);
            acc[i] = mfma16(af, bfr, acc[i]);
        }
    }
    #pragma unroll
    for (int i = 0; i < 4; ++i) {
        int n = (wave >> 1) + i * 4;
        #pragma unroll
        for (int r = 0; r < 4; ++r) {
            float h = acc[i][r];
            hbuf[(m * 16 + g * 4 + r) * FFSTH + n * 16 + r16] = (__bf16)(h > 0.f ? h : 0.f);
        }
    }
    __syncthreads();
    float w2v0 = ow2[lane], w2v1 = ow2[64 + lane], w2v2 = ow2[128 + lane], w2v3 = ow2[192 + lane];
    float bias2 = ob2[0];
    #pragma unroll
    for (int i = 0; i < 4; ++i) {
        int sm = wave * 4 + i;
        float part = (float)hbuf[sm * FFSTH + lane]       * w2v0
                   + (float)hbuf[sm * FFSTH + 64 + lane]  * w2v1
                   + (float)hbuf[sm * FFSTH + 128 + lane] * w2v2
                   + (float)hbuf[sm * FFSTH + 192 + lane] * w2v3;
        #pragma unroll
        for (int off = 32; off >= 1; off >>= 1) part += __shfl_xor(part, off);
        if (lane == 0) {
            float z = part + bias2;
            out[base + sm] = __builtin_amdgcn_rcpf(1.0f + __expf(-z));
        }
    }
}

extern "C" void kernel_launch(void* const* d_in, const int* in_sizes, int n_in,
                              void* d_out, int out_size, void* d_ws, size_t ws_size,
                              hipStream_t stream)
{
    const int*   dfeat = (const int*)d_in[0];
    const int*   sfeat = (const int*)d_in[1];
    const float* demb  = (const float*)d_in[2];
    const float* semb  = (const float*)d_in[3];
    const float* wq    = (const float*)d_in[4];
    const float* bq    = (const float*)d_in[5];
    const float* wk    = (const float*)d_in[6];
    const float* bk    = (const float*)d_in[7];
    const float* wv    = (const float*)d_in[8];
    const float* bv    = (const float*)d_in[9];
    const float* wo    = (const float*)d_in[10];
    const float* bo    = (const float*)d_in[11];
    const float* ln1g  = (const float*)d_in[12];
    const float* ln1b  = (const float*)d_in[13];
    const float* ln2g  = (const float*)d_in[14];
    const float* ln2b  = (const float*)d_in[15];
    const float* w1    = (const float*)d_in[16];
    const float* b1    = (const float*)d_in[17];
    const float* w2    = (const float*)d_in[18];
    const float* b2    = (const float*)d_in[19];
    const float* ow1   = (const float*)d_in[20];
    const float* ob1   = (const float*)d_in[21];
    const float* ow2   = (const float*)d_in[22];
    const float* ob2   = (const float*)d_in[23];

    __bf16* flatX = (__bf16*)d_ws;
    __bf16* pk    = ((__bf16*)d_ws) + FLATX_ELEMS;
    float*  pkb   = (float*)(pk + PK_TOTAL);      // folded biases, 1792 f32
    float* out = (float*)d_out;

    pack_weights<<<(PK_TOTAL + 255) / 256, 256, 0, stream>>>(wq, wk, wv, wo, w1, w2,
                                                             ow1, ln1g, ln2g, pk);
    fold_bias<<<(NLAYER * FB_PER_LAYER + 255) / 256, 256, 0, stream>>>(
        wq, wk, wv, w1, bq, bk, bv, b1, ln1b, ln2b, pkb);
    hstu_fused<<<NSAMP, 256, 0, stream>>>(dfeat, sfeat, demb, semb,
                                          bo, b2, pk, pkb, flatX);
    final_mlp<<<NSAMP / 32, 512, 0, stream>>>(flatX, pk + PK_OW1T, ob1, ow2, ob2, out);
}

// Round 15
// 679.194 us; speedup vs baseline: 1.1975x; 1.0713x over previous
//
#include <hip/hip_runtime.h>
#include <hip/hip_bf16.h>

#define NDENSE 13
#define NSPARSE 26
#define NFEAT 39
#define EDIM 64
#define NLAYER 4
#define FFDIM 256
#define VDN 50
#define VSN 50000
#define NSAMP 8192
#define LN_EPS 1e-5f

// Q pre-scale: HD^-0.5 * log2(e), folded into wqT/bq' at pack time
#define QSCL 0.5100697f
// gelu: x * sigmoid2(C1*x + C2*x^3), constants pre-multiplied by log2(e)
#define GC1 2.3022082f
#define GC2 0.10294324f

#define XST 72     // xb row stride (bf16), 144 B
#define QST 72     // Qb/Kb row stride
#define VST2 56    // Vt row stride (112 B, 16B-mult)
#define FST2 136   // ff row stride (272 B, 16B-mult)

// LDS layout (bytes) — 1 sample / block
#define OFF_XB 0             // xb [40][72]  = 5760
#define OFF_QB 5760          // Qb [48][72]  = 6912  (S-staging in A2; O after attn; ff in A4)
#define OFF_KB 12672         // Kb [48][72]  = 6912  (staging tail / ff tail)
#define OFF_VT 19584         // Vt [64][56]  = 7168  (LN scratch in A1/A4)
#define SMEM_TOTAL 26752
#define OFF_FF OFF_QB        // ff [48][136] = 13056 <= Qb+Kb = 13824
#define OFF_LNS OFF_VT       // LN rows [48][72] = 6912 <= 7168

// ---- packed (transposed, bf16, gamma/QSCL-folded) weights in d_ws after flatX ----
#define FLATX_ELEMS (8192L * NFEAT * EDIM)
#define PK_WKT 4096
#define PK_WVT 8192
#define PK_WOT 12288
#define PK_W1T 16384
#define PK_W2T 32768
#define PK_LAYER 49152
#define PK_OW1T 196608
#define PK_TOTAL 835584
#define FB_PER_LAYER 448     // folded biases: bq'(64) bk'(64) bv'(64) b1'(256), f32

typedef __bf16 bf16x8 __attribute__((ext_vector_type(8)));
typedef __bf16 bf16x4 __attribute__((ext_vector_type(4)));
typedef float f32x4 __attribute__((ext_vector_type(4)));

__device__ __forceinline__ f32x4 mfma16(bf16x8 a, bf16x8 b, f32x4 c) {
    return __builtin_amdgcn_mfma_f32_16x16x32_bf16(a, b, c, 0, 0, 0);
}

__device__ __forceinline__ float exp2_fast(float x) {
#if __has_builtin(__builtin_amdgcn_exp2f)
    return __builtin_amdgcn_exp2f(x);
#else
    return exp2f(x);
#endif
}
__device__ __forceinline__ float sigmoid2(float x) {
    return __builtin_amdgcn_rcpf(1.0f + exp2_fast(-x));
}
__device__ __forceinline__ float gelu_f(float x) {
    return x * sigmoid2(GC1 * x + GC2 * x * x * x);
}

__device__ __forceinline__ bf16x8 ldfrag(const __bf16* WT, int ld, int col, int k0) {
    return *(const bf16x8*)&WT[col * ld + k0];
}
__device__ __forceinline__ bf16x4 pk4(f32x4 v) {
    bf16x4 r; r[0]=(__bf16)v[0]; r[1]=(__bf16)v[1]; r[2]=(__bf16)v[2]; r[3]=(__bf16)v[3]; return r;
}
__device__ __forceinline__ void rmw4(__bf16* p, f32x4 a) {
    bf16x4 o = *(bf16x4*)p;
    f32x4 n = { (float)o[0]+a[0], (float)o[1]+a[1], (float)o[2]+a[2], (float)o[3]+a[3] };
    *(bf16x4*)p = pk4(n);
}

// Cooperative row-normalize of xb rows 0..47 (clamped) into LNS [48][72].
// 12 units over 4 waves; unit u handles rows 4u+g; 16 lanes (r16) x 4 cols each.
__device__ __forceinline__ void coop_ln(const __bf16* xb, __bf16* LNS,
                                        int w, int g, int r16) {
    for (int u = w; u < 12; u += 4) {
        int ql = 4 * u + g;
        int qlc = ql > 39 ? 39 : ql;
        bf16x4 v = *(const bf16x4*)&xb[qlc * XST + 4 * r16];
        float x0 = (float)v[0], x1 = (float)v[1], x2 = (float)v[2], x3 = (float)v[3];
        float s = x0 + x1 + x2 + x3;
        float ss = x0*x0 + x1*x1 + x2*x2 + x3*x3;
        s += __shfl_xor(s, 1);  ss += __shfl_xor(ss, 1);
        s += __shfl_xor(s, 2);  ss += __shfl_xor(ss, 2);
        s += __shfl_xor(s, 4);  ss += __shfl_xor(ss, 4);
        s += __shfl_xor(s, 8);  ss += __shfl_xor(ss, 8);
        float mn = s * (1.0f / 64.0f);
        float rs = rsqrtf(ss * (1.0f / 64.0f) - mn * mn + LN_EPS);
        f32x4 nv = { (x0 - mn) * rs, (x1 - mn) * rs,
                     (x2 - mn) * rs, (x3 - mn) * rs };
        *(bf16x4*)&LNS[ql * 72 + 4 * r16] = pk4(nv);
    }
}

// ---------------- weight pack: transpose + bf16, LN gamma (and QSCL) folded ----------------
__global__ __launch_bounds__(256)
void pack_weights(const float* __restrict__ wq, const float* __restrict__ wk,
                  const float* __restrict__ wv, const float* __restrict__ wo,
                  const float* __restrict__ w1, const float* __restrict__ w2,
                  const float* __restrict__ ow1, const float* __restrict__ ln1g,
                  const float* __restrict__ ln2g, __bf16* __restrict__ pk)
{
    int idx = blockIdx.x * 256 + threadIdx.x;
    if (idx >= PK_TOTAL) return;
    float v;
    if (idx < PK_OW1T) {
        int l = idx / PK_LAYER, r = idx - l * PK_LAYER;
        const float* src; const float* gam = nullptr; int sh, N, off;
        float extra = 1.0f;
        if (r < PK_WKT)      { src = wq + l * 4096;  sh = 6; N = 64;  off = r;           gam = ln1g + l*64; extra = QSCL; }
        else if (r < PK_WVT) { src = wk + l * 4096;  sh = 6; N = 64;  off = r - PK_WKT;  gam = ln1g + l*64; }
        else if (r < PK_WOT) { src = wv + l * 4096;  sh = 6; N = 64;  off = r - PK_WVT;  gam = ln1g + l*64; }
        else if (r < PK_W1T) { src = wo + l * 4096;  sh = 6; N = 64;  off = r - PK_WOT; }
        else if (r < PK_W2T) { src = w1 + l * 16384; sh = 6; N = 256; off = r - PK_W1T;  gam = ln2g + l*64; }
        else                 { src = w2 + l * 16384; sh = 8; N = 64;  off = r - PK_W2T; }
        int col = off >> sh, k = off & ((1 << sh) - 1);
        v = src[k * N + col] * extra;
        if (gam) v *= gam[k];
    } else {
        int off = idx - PK_OW1T;
        int col = off / 2496, k = off - col * 2496;
        v = ow1[k * 256 + col];
    }
    pk[idx] = (__bf16)v;
}

// ---------------- bias fold: b' = (b + beta @ W) [* QSCL for q] (f32) ----------------
__global__ __launch_bounds__(256)
void fold_bias(const float* __restrict__ wq, const float* __restrict__ wk,
               const float* __restrict__ wv, const float* __restrict__ w1,
               const float* __restrict__ bq, const float* __restrict__ bk,
               const float* __restrict__ bv, const float* __restrict__ b1,
               const float* __restrict__ ln1b, const float* __restrict__ ln2b,
               float* __restrict__ pkb)
{
    int idx = blockIdx.x * 256 + threadIdx.x;
    if (idx >= NLAYER * FB_PER_LAYER) return;
    int l = idx / FB_PER_LAYER, r = idx - l * FB_PER_LAYER;
    const float *W, *b, *beta; int col, N; float extra = 1.0f;
    if (r < 64)       { W = wq + l*4096;  b = bq + l*64;  beta = ln1b + l*64; col = r;       N = 64;  extra = QSCL; }
    else if (r < 128) { W = wk + l*4096;  b = bk + l*64;  beta = ln1b + l*64; col = r - 64;  N = 64;  }
    else if (r < 192) { W = wv + l*4096;  b = bv + l*64;  beta = ln1b + l*64; col = r - 128; N = 64;  }
    else              { W = w1 + l*16384; b = b1 + l*256; beta = ln2b + l*64; col = r - 192; N = 256; }
    float acc = b[col];
    for (int k = 0; k < 64; ++k) acc += beta[k] * W[k * N + col];
    pkb[idx] = acc * extra;
}

// ---------------- fused 4-layer transformer, 1 sample / block, 4 waves ----------------
__global__ __launch_bounds__(256, 4)
void hstu_fused(const int* __restrict__ dfeat, const int* __restrict__ sfeat,
                const float* __restrict__ demb, const float* __restrict__ semb,
                const float* __restrict__ bo, const float* __restrict__ b2,
                const __bf16* __restrict__ pk, const float* __restrict__ pkb,
                __bf16* __restrict__ flatX)
{
    __shared__ __align__(16) char smem[SMEM_TOTAL];
    __bf16* xb  = (__bf16*)(smem + OFF_XB);
    __bf16* Qb  = (__bf16*)(smem + OFF_QB);
    __bf16* Kb  = (__bf16*)(smem + OFF_KB);
    __bf16* Vt  = (__bf16*)(smem + OFF_VT);
    __bf16* ff  = (__bf16*)(smem + OFF_FF);
    __bf16* LNS = (__bf16*)(smem + OFF_LNS);

    const int tid = threadIdx.x;
    const int lane = tid & 63, w = tid >> 6;       // 4 waves
    const int g = lane >> 4, r16 = lane & 15;
    const int oc = w;                              // 16-col output strip
    const int s0 = blockIdx.x;                     // one sample

    // ---------------- embedding gather (row 39 = zero pad) ----------------
    for (int r = w; r < 40; r += 4) {
        float val = 0.0f;
        if (r < NFEAT) {
            if (r < NDENSE) {
                int idx = dfeat[s0 * NDENSE + r];
                val = demb[(r * VDN + idx) * EDIM + lane];
            } else {
                int idx = sfeat[s0 * NSPARSE + (r - NDENSE)];
                val = semb[((long)(r - NDENSE) * VSN + idx) * EDIM + lane];
            }
        }
        xb[r * XST + lane] = (__bf16)val;
    }
    __syncthreads();

    for (int lay = 0; lay < NLAYER; ++lay) {
        const __bf16* wqT = pk + lay * PK_LAYER;
        const __bf16* wkT = wqT + PK_WKT;
        const __bf16* wvT = wqT + PK_WVT;
        const __bf16* woT = wqT + PK_WOT;
        const __bf16* w1T = wqT + PK_W1T;
        const __bf16* w2T = wqT + PK_W2T;
        const float* fb   = pkb + lay * FB_PER_LAYER;   // bq' bk' bv' b1'
        const float* bo_l = bo + lay * EDIM;
        const float* b2_l = b2 + lay * EDIM;

        // ---- A1: cooperative LN1 -> LNS (=Vt, free now), then QKV projection ----
        coop_ln(xb, LNS, w, g, r16);
        __syncthreads();   // LNS ready

        bf16x8 lnB[3][2];
        #pragma unroll
        for (int tt = 0; tt < 3; ++tt) {
            lnB[tt][0] = *(const bf16x8*)&LNS[(16 * tt + r16) * 72 + 8 * g];
            lnB[tt][1] = *(const bf16x8*)&LNS[(16 * tt + r16) * 72 + 32 + 8 * g];
        }
        __syncthreads();   // all frags loaded; Vt may be overwritten now

        {
            const __bf16* Wm[3] = { wqT, wkT, wvT };
            #pragma unroll
            for (int m = 0; m < 3; ++m) {
                bf16x8 A0 = ldfrag(Wm[m], EDIM, 16 * oc + r16, 8 * g);
                bf16x8 A1 = ldfrag(Wm[m], EDIM, 16 * oc + r16, 32 + 8 * g);
                f32x4 bi4 = *(const f32x4*)&fb[m * 64 + 16 * oc + 4 * g];
                #pragma unroll
                for (int tt = 0; tt < 3; ++tt) {
                    f32x4 acc = bi4;
                    acc = mfma16(A0, lnB[tt][0], acc);
                    acc = mfma16(A1, lnB[tt][1], acc);
                    int q48 = 16 * tt + r16;
                    if (m == 0) {
                        *(bf16x4*)&Qb[q48 * QST + 16 * oc + 4 * g] = pk4(acc);
                    } else if (m == 1) {
                        *(bf16x4*)&Kb[q48 * QST + 16 * oc + 4 * g] = pk4(acc);
                    } else {
                        bool vz = q48 >= 39;   // zero pad token cols
                        #pragma unroll
                        for (int r = 0; r < 4; ++r)
                            Vt[(16 * oc + 4 * g + r) * VST2 + q48] =
                                vz ? (__bf16)0.0f : (__bf16)acc[r];
                    }
                }
            }
        }
        __syncthreads();   // B1: Q/K/Vt ready

        // ---- A2: attention; wave -> heads 2oc, 2oc+1; S via per-wave LDS staging ----
        {
            // preload all Q/K fragments (g==0 lanes hold data), then Qb/Kb become staging
            bf16x8 qf[2][3], kf[2][3];
            #pragma unroll
            for (int hh = 0; hh < 2; ++hh) {
                #pragma unroll
                for (int t = 0; t < 3; ++t) {
                    bf16x8 z = {};
                    qf[hh][t] = z; kf[hh][t] = z;
                    if (g == 0) {
                        qf[hh][t] = *(const bf16x8*)&Qb[(16*t + r16) * QST + 8*(2*oc + hh)];
                        kf[hh][t] = *(const bf16x8*)&Kb[(16*t + r16) * QST + 8*(2*oc + hh)];
                    }
                }
            }
            __syncthreads();   // Qb/Kb free -> per-wave S staging

            // staging: per wave [48 q] rows of 64 B (4x 16B blocks), XOR-swizzled by
            // key=(q>>1)&3 -> 16 lanes/quarter produce all 8 (q&1, block) combos twice
            // = 2-way bank access (free), and every b128 read stays 16B-aligned.
            char* st = (char*)Qb + w * 3072;

            const int sAh[3] = {0,0,1}, sAt[3] = {0,2,1};   // ts=0 tile (hh,kt) per ks
            const int sBh[3] = {0,1,1}, sBt[3] = {1,0,2};   // ts=1 tile
            f32x4 oacc[3];
            {
                f32x4 z = {0.f, 0.f, 0.f, 0.f};
                oacc[0] = z; oacc[1] = z; oacc[2] = z;
            }
            #pragma unroll
            for (int ks = 0; ks < 3; ++ks) {
                // stage the two S^T tiles of this ks: D[kk_loc=4g+r][q=r16] per qt
                #pragma unroll
                for (int ts = 0; ts < 2; ++ts) {
                    int hh = ts ? sBh[ks] : sAh[ks];
                    int kt = ts ? sBt[ks] : sAt[ks];
                    #pragma unroll
                    for (int qt = 0; qt < 3; ++qt) {
                        f32x4 acc = {0.f, 0.f, 0.f, 0.f};
                        acc = mfma16(kf[hh][kt], qf[hh][qt], acc);
                        f32x4 sg = { sigmoid2(acc[0]), sigmoid2(acc[1]),
                                     sigmoid2(acc[2]), sigmoid2(acc[3]) };
                        int q = 16 * qt + r16;
                        int key = (q >> 1) & 3;
                        int off = q * 64 + (((2 * ts + (g >> 1)) ^ key) << 4)
                                + ((g & 1) << 3);
                        *(bf16x4*)(st + off) = pk4(sg);
                    }
                }
                // PV: A = Vt (head-masked), B = staged S^T (slot_loc = 8g+j)
                int slot0 = 32 * ks + 8 * g;
                int side = slot0 >= 48 ? 1 : 0;
                int kk0 = slot0 - 48 * side;
                bf16x8 av = {};
                if (side == (r16 >> 3))
                    av = *(const bf16x8*)&Vt[(16 * oc + r16) * VST2 + kk0];
                #pragma unroll
                for (int qt = 0; qt < 3; ++qt) {
                    int q = 16 * qt + r16;
                    int roff = q * 64 + (((g ^ ((q >> 1) & 3)) << 4));
                    bf16x8 bfrag = *(const bf16x8*)(st + roff);
                    oacc[qt] = mfma16(av, bfrag, oacc[qt]);
                }
            }
            __syncthreads();   // all PV staging reads done -> Qb free for O

            // O overwrites Qb (this wave's column strip)
            #pragma unroll
            for (int qt = 0; qt < 3; ++qt) {
                int q48 = 16 * qt + r16;
                *(bf16x4*)&Qb[q48 * QST + 16 * oc + 4 * g] = pk4(oacc[qt]);
            }
        }
        __syncthreads();   // B2: O complete

        // ---- A3: O-proj + residual; wave -> outcol tile oc ----
        {
            bf16x8 A0 = ldfrag(woT, EDIM, 16 * oc + r16, 8 * g);
            bf16x8 A1 = ldfrag(woT, EDIM, 16 * oc + r16, 32 + 8 * g);
            f32x4 bo4 = *(const f32x4*)&bo_l[16 * oc + 4 * g];
            #pragma unroll
            for (int tt = 0; tt < 3; ++tt) {
                bf16x8 B0 = *(const bf16x8*)&Qb[(16 * tt + r16) * QST + 8 * g];
                bf16x8 B1 = *(const bf16x8*)&Qb[(16 * tt + r16) * QST + 32 + 8 * g];
                f32x4 acc = bo4;
                acc = mfma16(A0, B0, acc);
                acc = mfma16(A1, B1, acc);
                int ql = 16 * tt + r16;
                if (ql <= 39)
                    rmw4(&xb[ql * XST + 16 * oc + 4 * g], acc);
            }
        }
        __syncthreads();   // B3: xb updated; Qb/Kb (ff) and Vt (LNS) free

        // ---- A4: MLP; cooperative LN2 -> LNS, FF in two 128-col passes ----
        coop_ln(xb, LNS, w, g, r16);
        __syncthreads();   // LNS ready

        {
            bf16x8 upB[3][2];
            #pragma unroll
            for (int tt = 0; tt < 3; ++tt) {
                upB[tt][0] = *(const bf16x8*)&LNS[(16 * tt + r16) * 72 + 8 * g];
                upB[tt][1] = *(const bf16x8*)&LNS[(16 * tt + r16) * 72 + 32 + 8 * g];
            }
            f32x4 acc2[3];
            acc2[0] = *(const f32x4*)&b2_l[16 * oc + 4 * g];
            acc2[1] = acc2[0]; acc2[2] = acc2[0];

            #pragma unroll
            for (int p2 = 0; p2 < 2; ++p2) {
                // up: wave -> 2 local ffcol tiles of this 128-col pass
                #pragma unroll
                for (int fi = 0; fi < 2; ++fi) {
                    int ftl = 2 * w + fi;           // local tile 0..7
                    int ftg = 8 * p2 + ftl;         // global tile 0..15
                    bf16x8 A0 = ldfrag(w1T, EDIM, 16 * ftg + r16, 8 * g);
                    bf16x8 A1 = ldfrag(w1T, EDIM, 16 * ftg + r16, 32 + 8 * g);
                    f32x4 b14 = *(const f32x4*)&fb[192 + 16 * ftg + 4 * g];
                    #pragma unroll
                    for (int tt = 0; tt < 3; ++tt) {
                        f32x4 acc = b14;
                        acc = mfma16(A0, upB[tt][0], acc);
                        acc = mfma16(A1, upB[tt][1], acc);
                        f32x4 gl = { gelu_f(acc[0]), gelu_f(acc[1]),
                                     gelu_f(acc[2]), gelu_f(acc[3]) };
                        *(bf16x4*)&ff[(16 * tt + r16) * FST2 + 16 * ftl + 4 * g] = pk4(gl);
                    }
                }
                __syncthreads();   // ff pass ready

                // down: wave -> outcol tile oc, accumulate across passes
                #pragma unroll
                for (int tt = 0; tt < 3; ++tt) {
                    #pragma unroll
                    for (int kf2 = 0; kf2 < 4; ++kf2) {
                        bf16x8 Af = ldfrag(w2T, FFDIM, 16 * oc + r16,
                                           128 * p2 + 32 * kf2 + 8 * g);
                        bf16x8 Bf = *(const bf16x8*)&ff[(16 * tt + r16) * FST2
                                                        + 32 * kf2 + 8 * g];
                        acc2[tt] = mfma16(Af, Bf, acc2[tt]);
                    }
                }
                __syncthreads();   // ff consumed; next pass may overwrite
            }
            // residual add
            #pragma unroll
            for (int tt = 0; tt < 3; ++tt) {
                int ql = 16 * tt + r16;
                if (ql <= 39)
                    rmw4(&xb[ql * XST + 16 * oc + 4 * g], acc2[tt]);
            }
        }
        __syncthreads();   // layer end: xb complete
    }

    // ---------------- write flat activations ----------------
    for (int r = w; r < NFEAT; r += 4)
        flatX[((long)s0 * NFEAT + r) * EDIM + lane] = xb[r * XST + lane];
}

// ---------------- head MLP ----------------
#define FFSTH 264
__global__ __launch_bounds__(512)
void final_mlp(const __bf16* __restrict__ flatX, const __bf16* __restrict__ ow1T,
               const float* __restrict__ ob1, const float* __restrict__ ow2,
               const float* __restrict__ ob2, float* __restrict__ out)
{
    __shared__ __bf16 hbuf[32 * FFSTH];
    const int tid = threadIdx.x, lane = tid & 63, wave = tid >> 6;
    const int g = lane >> 4, r16 = lane & 15;
    const int m = wave & 1;
    const long base = (long)blockIdx.x * 32;
    const long arow = (base + m * 16 + r16) * (long)(NFEAT * EDIM);

    f32x4 acc[4];
    #pragma unroll
    for (int i = 0; i < 4; ++i) {
        int n = (wave >> 1) + i * 4;
        float bz = ob1[n * 16 + r16];
        f32x4 t = {bz, bz, bz, bz};
        acc[i] = t;
    }
    for (int kf = 0; kf < 78; ++kf) {
        bf16x8 af = *(const bf16x8*)&flatX[arow + kf * 32 + g * 8];
        #pragma unroll
        for (int i = 0; i < 4; ++i) {
            int n = (wave >> 1) + i * 4;
            bf16x8 bfr = ldfrag(ow1T, NFEAT * EDIM, n * 16 + r16, kf * 32 + g * 8);
            acc[i] = mfma16(af, bfr, acc[i]);
        }
    }
    #pragma unroll
    for (int i = 0; i < 4; ++i) {
        int n = (wave >> 1) + i * 4;
        #pragma unroll
        for (int r = 0; r < 4; ++r) {
            float h = acc[i][r];
            hbuf[(m * 16 + g * 4 + r) * FFSTH + n * 16 + r16] = (__bf16)(h > 0.f ? h : 0.f);
        }
    }
    __syncthreads();
    float w2v0 = ow2[lane], w2v1 = ow2[64 + lane], w2v2 = ow2[128 + lane], w2v3 = ow2[192 + lane];
    float bias2 = ob2[0];
    #pragma unroll
    for (int i = 0; i < 4; ++i) {
        int sm = wave * 4 + i;
        float part = (float)hbuf[sm * FFSTH + lane]       * w2v0
                   + (float)hbuf[sm * FFSTH + 64 + lane]  * w2v1
                   + (float)hbuf[sm * FFSTH + 128 + lane] * w2v2
                   + (float)hbuf[sm * FFSTH + 192 + lane] * w2v3;
        #pragma unroll
        for (int off = 32; off >= 1; off >>= 1) part += __shfl_xor(part, off);
        if (lane == 0) {
            float z = part + bias2;
            out[base + sm] = __builtin_amdgcn_rcpf(1.0f + __expf(-z));
        }
    }
}

extern "C" void kernel_launch(void* const* d_in, const int* in_sizes, int n_in,
                              void* d_out, int out_size, void* d_ws, size_t ws_size,
                              hipStream_t stream)
{
    const int*   dfeat = (const int*)d_in[0];
    const int*   sfeat = (const int*)d_in[1];
    const float* demb  = (const float*)d_in[2];
    const float* semb  = (const float*)d_in[3];
    const float* wq    = (const float*)d_in[4];
    const float* bq    = (const float*)d_in[5];
    const float* wk    = (const float*)d_in[6];
    const float* bk    = (const float*)d_in[7];
    const float* wv    = (const float*)d_in[8];
    const float* bv    = (const float*)d_in[9];
    const float* wo    = (const float*)d_in[10];
    const float* bo    = (const float*)d_in[11];
    const float* ln1g  = (const float*)d_in[12];
    const float* ln1b  = (const float*)d_in[13];
    const float* ln2g  = (const float*)d_in[14];
    const float* ln2b  = (const float*)d_in[15];
    const float* w1    = (const float*)d_in[16];
    const float* b1    = (const float*)d_in[17];
    const float* w2    = (const float*)d_in[18];
    const float* b2    = (const float*)d_in[19];
    const float* ow1   = (const float*)d_in[20];
    const float* ob1   = (const float*)d_in[21];
    const float* ow2   = (const float*)d_in[22];
    const float* ob2   = (const float*)d_in[23];

    __bf16* flatX = (__bf16*)d_ws;
    __bf16* pk    = ((__bf16*)d_ws) + FLATX_ELEMS;
    float*  pkb   = (float*)(pk + PK_TOTAL);      // folded biases, 1792 f32
    float* out = (float*)d_out;

    pack_weights<<<(PK_TOTAL + 255) / 256, 256, 0, stream>>>(wq, wk, wv, wo, w1, w2,
                                                             ow1, ln1g, ln2g, pk);
    fold_bias<<<(NLAYER * FB_PER_LAYER + 255) / 256, 256, 0, stream>>>(
        wq, wk, wv, w1, bq, bk, bv, b1, ln1b, ln2b, pkb);
    hstu_fused<<<NSAMP, 256, 0, stream>>>(dfeat, sfeat, demb, semb,
                                          bo, b2, pk, pkb, flatX);
    final_mlp<<<NSAMP / 32, 512, 0, stream>>>(flatX, pk + PK_OW1T, ob1, ow2, ob2, out);
}

// Round 16
// 674.381 us; speedup vs baseline: 1.2061x; 1.0071x over previous
//
#include <hip/hip_runtime.h>
#include <hip/hip_bf16.h>

#define NDENSE 13
#define NSPARSE 26
#define NFEAT 39
#define EDIM 64
#define NLAYER 4
#define FFDIM 256
#define VDN 50
#define VSN 50000
#define NSAMP 8192
#define LN_EPS 1e-5f

// Q pre-scale: HD^-0.5 * log2(e), folded into wqT/bq' at pack time
#define QSCL 0.5100697f
// gelu: x * sigmoid2(C1*x + C2*x^3), constants pre-multiplied by log2(e)
#define GC1 2.3022082f
#define GC2 0.10294324f

#define XST 72     // xb row stride (bf16), 144 B
#define QST 72     // Qb/Kb row stride
#define VST2 56    // Vt row stride (112 B, 16B-mult)
#define FST2 136   // ff row stride (272 B, 16B-mult)
#define LST 72     // LNS row stride (bf16)

// LDS layout (bytes) — 1 sample / block
#define OFF_XB 0             // xb  [40][72] = 5760
#define OFF_QB 5760          // Qb  [48][72] = 6912  (S-staging in A2; ff in A4)
#define OFF_KB 12672         // Kb  [48][72] = 6912  (staging tail / ff tail)
#define OFF_VT 19584         // Vt  [64][56] = 7168
#define OFF_LNS 26752        // LNS [48][72] = 6912  (LN frags; O after attention)
#define SMEM_TOTAL 33664     // <= 40960 -> 4 blocks/CU
#define OFF_FF OFF_QB        // ff [48][136] = 13056 <= Qb+Kb = 13824

// ---- packed (transposed, bf16, gamma/QSCL-folded) weights in d_ws after flatX ----
#define FLATX_ELEMS (8192L * NFEAT * EDIM)
#define PK_WKT 4096
#define PK_WVT 8192
#define PK_WOT 12288
#define PK_W1T 16384
#define PK_W2T 32768
#define PK_LAYER 49152
#define PK_OW1T 196608
#define PK_TOTAL 835584
#define FB_PER_LAYER 448     // folded biases: bq'(64) bk'(64) bv'(64) b1'(256), f32

typedef __bf16 bf16x8 __attribute__((ext_vector_type(8)));
typedef __bf16 bf16x4 __attribute__((ext_vector_type(4)));
typedef float f32x4 __attribute__((ext_vector_type(4)));

__device__ __forceinline__ f32x4 mfma16(bf16x8 a, bf16x8 b, f32x4 c) {
    return __builtin_amdgcn_mfma_f32_16x16x32_bf16(a, b, c, 0, 0, 0);
}

__device__ __forceinline__ float exp2_fast(float x) {
#if __has_builtin(__builtin_amdgcn_exp2f)
    return __builtin_amdgcn_exp2f(x);
#else
    return exp2f(x);
#endif
}
__device__ __forceinline__ float sigmoid2(float x) {
    return __builtin_amdgcn_rcpf(1.0f + exp2_fast(-x));
}
__device__ __forceinline__ float gelu_f(float x) {
    return x * sigmoid2(GC1 * x + GC2 * x * x * x);
}

__device__ __forceinline__ bf16x8 ldfrag(const __bf16* WT, int ld, int col, int k0) {
    return *(const bf16x8*)&WT[col * ld + k0];
}
__device__ __forceinline__ bf16x4 pk4(f32x4 v) {
    bf16x4 r; r[0]=(__bf16)v[0]; r[1]=(__bf16)v[1]; r[2]=(__bf16)v[2]; r[3]=(__bf16)v[3]; return r;
}
__device__ __forceinline__ void rmw4(__bf16* p, f32x4 a) {
    bf16x4 o = *(bf16x4*)p;
    f32x4 n = { (float)o[0]+a[0], (float)o[1]+a[1], (float)o[2]+a[2], (float)o[3]+a[3] };
    *(bf16x4*)p = pk4(n);
}

// Cooperative row-normalize of xb rows 0..47 (clamped) into LNS [48][LST].
// 12 units over 4 waves; unit u handles rows 4u+g; 16 lanes (r16) x 4 cols each.
__device__ __forceinline__ void coop_ln(const __bf16* xb, __bf16* LNS,
                                        int w, int g, int r16) {
    for (int u = w; u < 12; u += 4) {
        int ql = 4 * u + g;
        int qlc = ql > 39 ? 39 : ql;
        bf16x4 v = *(const bf16x4*)&xb[qlc * XST + 4 * r16];
        float x0 = (float)v[0], x1 = (float)v[1], x2 = (float)v[2], x3 = (float)v[3];
        float s = x0 + x1 + x2 + x3;
        float ss = x0*x0 + x1*x1 + x2*x2 + x3*x3;
        s += __shfl_xor(s, 1);  ss += __shfl_xor(ss, 1);
        s += __shfl_xor(s, 2);  ss += __shfl_xor(ss, 2);
        s += __shfl_xor(s, 4);  ss += __shfl_xor(ss, 4);
        s += __shfl_xor(s, 8);  ss += __shfl_xor(ss, 8);
        float mn = s * (1.0f / 64.0f);
        float rs = rsqrtf(ss * (1.0f / 64.0f) - mn * mn + LN_EPS);
        f32x4 nv = { (x0 - mn) * rs, (x1 - mn) * rs,
                     (x2 - mn) * rs, (x3 - mn) * rs };
        *(bf16x4*)&LNS[ql * LST + 4 * r16] = pk4(nv);
    }
}

// ---------------- weight pack: transpose + bf16, LN gamma (and QSCL) folded ----------------
__global__ __launch_bounds__(256)
void pack_weights(const float* __restrict__ wq, const float* __restrict__ wk,
                  const float* __restrict__ wv, const float* __restrict__ wo,
                  const float* __restrict__ w1, const float* __restrict__ w2,
                  const float* __restrict__ ow1, const float* __restrict__ ln1g,
                  const float* __restrict__ ln2g, __bf16* __restrict__ pk)
{
    int idx = blockIdx.x * 256 + threadIdx.x;
    if (idx >= PK_TOTAL) return;
    float v;
    if (idx < PK_OW1T) {
        int l = idx / PK_LAYER, r = idx - l * PK_LAYER;
        const float* src; const float* gam = nullptr; int sh, N, off;
        float extra = 1.0f;
        if (r < PK_WKT)      { src = wq + l * 4096;  sh = 6; N = 64;  off = r;           gam = ln1g + l*64; extra = QSCL; }
        else if (r < PK_WVT) { src = wk + l * 4096;  sh = 6; N = 64;  off = r - PK_WKT;  gam = ln1g + l*64; }
        else if (r < PK_WOT) { src = wv + l * 4096;  sh = 6; N = 64;  off = r - PK_WVT;  gam = ln1g + l*64; }
        else if (r < PK_W1T) { src = wo + l * 4096;  sh = 6; N = 64;  off = r - PK_WOT; }
        else if (r < PK_W2T) { src = w1 + l * 16384; sh = 6; N = 256; off = r - PK_W1T;  gam = ln2g + l*64; }
        else                 { src = w2 + l * 16384; sh = 8; N = 64;  off = r - PK_W2T; }
        int col = off >> sh, k = off & ((1 << sh) - 1);
        v = src[k * N + col] * extra;
        if (gam) v *= gam[k];
    } else {
        int off = idx - PK_OW1T;
        int col = off / 2496, k = off - col * 2496;
        v = ow1[k * 256 + col];
    }
    pk[idx] = (__bf16)v;
}

// ---------------- bias fold: b' = (b + beta @ W) [* QSCL for q] (f32) ----------------
__global__ __launch_bounds__(256)
void fold_bias(const float* __restrict__ wq, const float* __restrict__ wk,
               const float* __restrict__ wv, const float* __restrict__ w1,
               const float* __restrict__ bq, const float* __restrict__ bk,
               const float* __restrict__ bv, const float* __restrict__ b1,
               const float* __restrict__ ln1b, const float* __restrict__ ln2b,
               float* __restrict__ pkb)
{
    int idx = blockIdx.x * 256 + threadIdx.x;
    if (idx >= NLAYER * FB_PER_LAYER) return;
    int l = idx / FB_PER_LAYER, r = idx - l * FB_PER_LAYER;
    const float *W, *b, *beta; int col, N; float extra = 1.0f;
    if (r < 64)       { W = wq + l*4096;  b = bq + l*64;  beta = ln1b + l*64; col = r;       N = 64;  extra = QSCL; }
    else if (r < 128) { W = wk + l*4096;  b = bk + l*64;  beta = ln1b + l*64; col = r - 64;  N = 64;  }
    else if (r < 192) { W = wv + l*4096;  b = bv + l*64;  beta = ln1b + l*64; col = r - 128; N = 64;  }
    else              { W = w1 + l*16384; b = b1 + l*256; beta = ln2b + l*64; col = r - 192; N = 256; }
    float acc = b[col];
    for (int k = 0; k < 64; ++k) acc += beta[k] * W[k * N + col];
    pkb[idx] = acc * extra;
}

// ---------------- fused 4-layer transformer, 1 sample / block, 4 waves ----------------
__global__ __launch_bounds__(256, 4)
void hstu_fused(const int* __restrict__ dfeat, const int* __restrict__ sfeat,
                const float* __restrict__ demb, const float* __restrict__ semb,
                const float* __restrict__ bo, const float* __restrict__ b2,
                const __bf16* __restrict__ pk, const float* __restrict__ pkb,
                __bf16* __restrict__ flatX)
{
    __shared__ __align__(16) char smem[SMEM_TOTAL];
    __bf16* xb  = (__bf16*)(smem + OFF_XB);
    __bf16* Qb  = (__bf16*)(smem + OFF_QB);
    __bf16* Kb  = (__bf16*)(smem + OFF_KB);
    __bf16* Vt  = (__bf16*)(smem + OFF_VT);
    __bf16* ff  = (__bf16*)(smem + OFF_FF);
    __bf16* LNS = (__bf16*)(smem + OFF_LNS);

    const int tid = threadIdx.x;
    const int lane = tid & 63, w = tid >> 6;       // 4 waves
    const int g = lane >> 4, r16 = lane & 15;
    const int oc = w;                              // 16-col output strip
    const int s0 = blockIdx.x;                     // one sample

    // ---------------- embedding gather (row 39 = zero pad) ----------------
    for (int r = w; r < 40; r += 4) {
        float val = 0.0f;
        if (r < NFEAT) {
            if (r < NDENSE) {
                int idx = dfeat[s0 * NDENSE + r];
                val = demb[(r * VDN + idx) * EDIM + lane];
            } else {
                int idx = sfeat[s0 * NSPARSE + (r - NDENSE)];
                val = semb[((long)(r - NDENSE) * VSN + idx) * EDIM + lane];
            }
        }
        xb[r * XST + lane] = (__bf16)val;
    }
    __syncthreads();

    for (int lay = 0; lay < NLAYER; ++lay) {
        const __bf16* wqT = pk + lay * PK_LAYER;
        const __bf16* wkT = wqT + PK_WKT;
        const __bf16* wvT = wqT + PK_WVT;
        const __bf16* woT = wqT + PK_WOT;
        const __bf16* w1T = wqT + PK_W1T;
        const __bf16* w2T = wqT + PK_W2T;
        const float* fb   = pkb + lay * FB_PER_LAYER;   // bq' bk' bv' b1'
        const float* bo_l = bo + lay * EDIM;
        const float* b2_l = b2 + lay * EDIM;

        // ---- A1: cooperative LN1 -> LNS (dedicated), then QKV projection ----
        coop_ln(xb, LNS, w, g, r16);
        __syncthreads();   // LNS ready

        bf16x8 lnB[3][2];
        #pragma unroll
        for (int tt = 0; tt < 3; ++tt) {
            lnB[tt][0] = *(const bf16x8*)&LNS[(16 * tt + r16) * LST + 8 * g];
            lnB[tt][1] = *(const bf16x8*)&LNS[(16 * tt + r16) * LST + 32 + 8 * g];
        }
        // no sync needed: LNS is not overwritten until A2's O-write, which is
        // after B1 (all waves have loaded lnB by then).

        {
            const __bf16* Wm[3] = { wqT, wkT, wvT };
            #pragma unroll
            for (int m = 0; m < 3; ++m) {
                bf16x8 A0 = ldfrag(Wm[m], EDIM, 16 * oc + r16, 8 * g);
                bf16x8 A1 = ldfrag(Wm[m], EDIM, 16 * oc + r16, 32 + 8 * g);
                f32x4 bi4 = *(const f32x4*)&fb[m * 64 + 16 * oc + 4 * g];
                #pragma unroll
                for (int tt = 0; tt < 3; ++tt) {
                    f32x4 acc = bi4;
                    acc = mfma16(A0, lnB[tt][0], acc);
                    acc = mfma16(A1, lnB[tt][1], acc);
                    int q48 = 16 * tt + r16;
                    if (m == 0) {
                        *(bf16x4*)&Qb[q48 * QST + 16 * oc + 4 * g] = pk4(acc);
                    } else if (m == 1) {
                        *(bf16x4*)&Kb[q48 * QST + 16 * oc + 4 * g] = pk4(acc);
                    } else {
                        bool vz = q48 >= 39;   // zero pad token cols
                        #pragma unroll
                        for (int r = 0; r < 4; ++r)
                            Vt[(16 * oc + 4 * g + r) * VST2 + q48] =
                                vz ? (__bf16)0.0f : (__bf16)acc[r];
                    }
                }
            }
        }
        __syncthreads();   // B1: Q/K/Vt ready

        // ---- A2: attention; wave -> heads 2oc, 2oc+1; S via per-wave LDS staging ----
        {
            // preload all Q/K fragments (g==0 lanes hold data), then Qb/Kb become staging
            bf16x8 qf[2][3], kf[2][3];
            #pragma unroll
            for (int hh = 0; hh < 2; ++hh) {
                #pragma unroll
                for (int t = 0; t < 3; ++t) {
                    bf16x8 z = {};
                    qf[hh][t] = z; kf[hh][t] = z;
                    if (g == 0) {
                        qf[hh][t] = *(const bf16x8*)&Qb[(16*t + r16) * QST + 8*(2*oc + hh)];
                        kf[hh][t] = *(const bf16x8*)&Kb[(16*t + r16) * QST + 8*(2*oc + hh)];
                    }
                }
            }
            __syncthreads();   // Qb/Kb free -> per-wave S staging

            // staging: per wave [48 q] rows of 64 B (4x 16B blocks), XOR-swizzled by
            // key=(q>>1)&3 -> 2-way bank access (free), all reads 16B-aligned.
            char* st = (char*)Qb + w * 3072;

            const int sAh[3] = {0,0,1}, sAt[3] = {0,2,1};   // ts=0 tile (hh,kt) per ks
            const int sBh[3] = {0,1,1}, sBt[3] = {1,0,2};   // ts=1 tile
            f32x4 oacc[3];
            {
                f32x4 z = {0.f, 0.f, 0.f, 0.f};
                oacc[0] = z; oacc[1] = z; oacc[2] = z;
            }
            #pragma unroll
            for (int ks = 0; ks < 3; ++ks) {
                // stage the two S^T tiles of this ks: D[kk_loc=4g+r][q=r16] per qt
                #pragma unroll
                for (int ts = 0; ts < 2; ++ts) {
                    int hh = ts ? sBh[ks] : sAh[ks];
                    int kt = ts ? sBt[ks] : sAt[ks];
                    #pragma unroll
                    for (int qt = 0; qt < 3; ++qt) {
                        f32x4 acc = {0.f, 0.f, 0.f, 0.f};
                        acc = mfma16(kf[hh][kt], qf[hh][qt], acc);
                        f32x4 sg = { sigmoid2(acc[0]), sigmoid2(acc[1]),
                                     sigmoid2(acc[2]), sigmoid2(acc[3]) };
                        int q = 16 * qt + r16;
                        int key = (q >> 1) & 3;
                        int off = q * 64 + (((2 * ts + (g >> 1)) ^ key) << 4)
                                + ((g & 1) << 3);
                        *(bf16x4*)(st + off) = pk4(sg);
                    }
                }
                // PV: A = Vt (head-masked), B = staged S^T (slot_loc = 8g+j)
                int slot0 = 32 * ks + 8 * g;
                int side = slot0 >= 48 ? 1 : 0;
                int kk0 = slot0 - 48 * side;
                bf16x8 av = {};
                if (side == (r16 >> 3))
                    av = *(const bf16x8*)&Vt[(16 * oc + r16) * VST2 + kk0];
                #pragma unroll
                for (int qt = 0; qt < 3; ++qt) {
                    int q = 16 * qt + r16;
                    int roff = q * 64 + (((g ^ ((q >> 1) & 3)) << 4));
                    bf16x8 bfrag = *(const bf16x8*)(st + roff);
                    oacc[qt] = mfma16(av, bfrag, oacc[qt]);
                }
            }
            // O goes to LNS (free since B1) -> no sync needed before the write
            #pragma unroll
            for (int qt = 0; qt < 3; ++qt) {
                int q48 = 16 * qt + r16;
                *(bf16x4*)&LNS[q48 * LST + 16 * oc + 4 * g] = pk4(oacc[qt]);
            }
        }
        __syncthreads();   // B2: O complete in LNS

        // ---- A3: O-proj + residual; wave -> outcol tile oc (O read from LNS) ----
        {
            bf16x8 A0 = ldfrag(woT, EDIM, 16 * oc + r16, 8 * g);
            bf16x8 A1 = ldfrag(woT, EDIM, 16 * oc + r16, 32 + 8 * g);
            f32x4 bo4 = *(const f32x4*)&bo_l[16 * oc + 4 * g];
            #pragma unroll
            for (int tt = 0; tt < 3; ++tt) {
                bf16x8 B0 = *(const bf16x8*)&LNS[(16 * tt + r16) * LST + 8 * g];
                bf16x8 B1 = *(const bf16x8*)&LNS[(16 * tt + r16) * LST + 32 + 8 * g];
                f32x4 acc = bo4;
                acc = mfma16(A0, B0, acc);
                acc = mfma16(A1, B1, acc);
                int ql = 16 * tt + r16;
                if (ql <= 39)
                    rmw4(&xb[ql * XST + 16 * oc + 4 * g], acc);
            }
        }
        __syncthreads();   // B3: xb updated; LNS free; Qb/Kb (ff) free

        // ---- A4: MLP; cooperative LN2 -> LNS, FF in two 128-col passes ----
        coop_ln(xb, LNS, w, g, r16);
        __syncthreads();   // LNS ready

        {
            bf16x8 upB[3][2];
            #pragma unroll
            for (int tt = 0; tt < 3; ++tt) {
                upB[tt][0] = *(const bf16x8*)&LNS[(16 * tt + r16) * LST + 8 * g];
                upB[tt][1] = *(const bf16x8*)&LNS[(16 * tt + r16) * LST + 32 + 8 * g];
            }
            f32x4 acc2[3];
            acc2[0] = *(const f32x4*)&b2_l[16 * oc + 4 * g];
            acc2[1] = acc2[0]; acc2[2] = acc2[0];

            #pragma unroll
            for (int p2 = 0; p2 < 2; ++p2) {
                // up: wave -> 2 local ffcol tiles of this 128-col pass
                #pragma unroll
                for (int fi = 0; fi < 2; ++fi) {
                    int ftl = 2 * w + fi;           // local tile 0..7
                    int ftg = 8 * p2 + ftl;         // global tile 0..15
                    bf16x8 A0 = ldfrag(w1T, EDIM, 16 * ftg + r16, 8 * g);
                    bf16x8 A1 = ldfrag(w1T, EDIM, 16 * ftg + r16, 32 + 8 * g);
                    f32x4 b14 = *(const f32x4*)&fb[192 + 16 * ftg + 4 * g];
                    #pragma unroll
                    for (int tt = 0; tt < 3; ++tt) {
                        f32x4 acc = b14;
                        acc = mfma16(A0, upB[tt][0], acc);
                        acc = mfma16(A1, upB[tt][1], acc);
                        f32x4 gl = { gelu_f(acc[0]), gelu_f(acc[1]),
                                     gelu_f(acc[2]), gelu_f(acc[3]) };
                        *(bf16x4*)&ff[(16 * tt + r16) * FST2 + 16 * ftl + 4 * g] = pk4(gl);
                    }
                }
                __syncthreads();   // ff pass ready

                // down: wave -> outcol tile oc, accumulate across passes
                #pragma unroll
                for (int tt = 0; tt < 3; ++tt) {
                    #pragma unroll
                    for (int kf2 = 0; kf2 < 4; ++kf2) {
                        bf16x8 Af = ldfrag(w2T, FFDIM, 16 * oc + r16,
                                           128 * p2 + 32 * kf2 + 8 * g);
                        bf16x8 Bf = *(const bf16x8*)&ff[(16 * tt + r16) * FST2
                                                        + 32 * kf2 + 8 * g];
                        acc2[tt] = mfma16(Af, Bf, acc2[tt]);
                    }
                }
                __syncthreads();   // ff consumed; next pass may overwrite
            }
            // residual add
            #pragma unroll
            for (int tt = 0; tt < 3; ++tt) {
                int ql = 16 * tt + r16;
                if (ql <= 39)
                    rmw4(&xb[ql * XST + 16 * oc + 4 * g], acc2[tt]);
            }
        }
        __syncthreads();   // layer end: xb complete
    }

    // ---------------- write flat activations ----------------
    for (int r = w; r < NFEAT; r += 4)
        flatX[((long)s0 * NFEAT + r) * EDIM + lane] = xb[r * XST + lane];
}

// ---------------- head MLP ----------------
#define FFSTH 264
__global__ __launch_bounds__(512)
void final_mlp(const __bf16* __restrict__ flatX, const __bf16* __restrict__ ow1T,
               const float* __restrict__ ob1, const float* __restrict__ ow2,
               const float* __restrict__ ob2, float* __restrict__ out)
{
    __shared__ __bf16 hbuf[32 * FFSTH];
    const int tid = threadIdx.x, lane = tid & 63, wave = tid >> 6;
    const int g = lane >> 4, r16 = lane & 15;
    const int m = wave & 1;
    const long base = (long)blockIdx.x * 32;
    const long arow = (base + m * 16 + r16) * (long)(NFEAT * EDIM);

    f32x4 acc[4];
    #pragma unroll
    for (int i = 0; i < 4; ++i) {
        int n = (wave >> 1) + i * 4;
        float bz = ob1[n * 16 + r16];
        f32x4 t = {bz, bz, bz, bz};
        acc[i] = t;
    }
    for (int kf = 0; kf < 78; ++kf) {
        bf16x8 af = *(const bf16x8*)&flatX[arow + kf * 32 + g * 8];
        #pragma unroll
        for (int i = 0; i < 4; ++i) {
            int n = (wave >> 1) + i * 4;
            bf16x8 bfr = ldfrag(ow1T, NFEAT * EDIM, n * 16 + r16, kf * 32 + g * 8);
            acc[i] = mfma16(af, bfr, acc[i]);
        }
    }
    #pragma unroll
    for (int i = 0; i < 4; ++i) {
        int n = (wave >> 1) + i * 4;
        #pragma unroll
        for (int r = 0; r < 4; ++r) {
            float h = acc[i][r];
            hbuf[(m * 16 + g * 4 + r) * FFSTH + n * 16 + r16] = (__bf16)(h > 0.f ? h : 0.f);
        }
    }
    __syncthreads();
    float w2v0 = ow2[lane], w2v1 = ow2[64 + lane], w2v2 = ow2[128 + lane], w2v3 = ow2[192 + lane];
    float bias2 = ob2[0];
    #pragma unroll
    for (int i = 0; i < 4; ++i) {
        int sm = wave * 4 + i;
        float part = (float)hbuf[sm * FFSTH + lane]       * w2v0
                   + (float)hbuf[sm * FFSTH + 64 + lane]  * w2v1
                   + (float)hbuf[sm * FFSTH + 128 + lane] * w2v2
                   + (float)hbuf[sm * FFSTH + 192 + lane] * w2v3;
        #pragma unroll
        for (int off = 32; off >= 1; off >>= 1) part += __shfl_xor(part, off);
        if (lane == 0) {
            float z = part + bias2;
            out[base + sm] = __builtin_amdgcn_rcpf(1.0f + __expf(-z));
        }
    }
}

extern "C" void kernel_launch(void* const* d_in, const int* in_sizes, int n_in,
                              void* d_out, int out_size, void* d_ws, size_t ws_size,
                              hipStream_t stream)
{
    const int*   dfeat = (const int*)d_in[0];
    const int*   sfeat = (const int*)d_in[1];
    const float* demb  = (const float*)d_in[2];
    const float* semb  = (const float*)d_in[3];
    const float* wq    = (const float*)d_in[4];
    const float* bq    = (const float*)d_in[5];
    const float* wk    = (const float*)d_in[6];
    const float* bk    = (const float*)d_in[7];
    const float* wv    = (const float*)d_in[8];
    const float* bv    = (const float*)d_in[9];
    const float* wo    = (const float*)d_in[10];
    const float* bo    = (const float*)d_in[11];
    const float* ln1g  = (const float*)d_in[12];
    const float* ln1b  = (const float*)d_in[13];
    const float* ln2g  = (const float*)d_in[14];
    const float* ln2b  = (const float*)d_in[15];
    const float* w1    = (const float*)d_in[16];
    const float* b1    = (const float*)d_in[17];
    const float* w2    = (const float*)d_in[18];
    const float* b2    = (const float*)d_in[19];
    const float* ow1   = (const float*)d_in[20];
    const float* ob1   = (const float*)d_in[21];
    const float* ow2   = (const float*)d_in[22];
    const float* ob2   = (const float*)d_in[23];

    __bf16* flatX = (__bf16*)d_ws;
    __bf16* pk    = ((__bf16*)d_ws) + FLATX_ELEMS;
    float*  pkb   = (float*)(pk + PK_TOTAL);      // folded biases, 1792 f32
    float* out = (float*)d_out;

    pack_weights<<<(PK_TOTAL + 255) / 256, 256, 0, stream>>>(wq, wk, wv, wo, w1, w2,
                                                             ow1, ln1g, ln2g, pk);
    fold_bias<<<(NLAYER * FB_PER_LAYER + 255) / 256, 256, 0, stream>>>(
        wq, wk, wv, w1, bq, bk, bv, b1, ln1b, ln2b, pkb);
    hstu_fused<<<NSAMP, 256, 0, stream>>>(dfeat, sfeat, demb, semb,
                                          bo, b2, pk, pkb, flatX);
    final_mlp<<<NSAMP / 32, 512, 0, stream>>>(flatX, pk + PK_OW1T, ob1, ow2, ob2, out);
}